// Round 8
// baseline (7436.744 us; speedup 1.0000x reference)
//
#include <hip/hip_runtime.h>

typedef unsigned int  uint32;
typedef unsigned long long u64;
typedef unsigned short bf16u;
typedef __attribute__((ext_vector_type(8))) short s8v;     // 8 bf16 (4 VGPRs)
typedef __attribute__((ext_vector_type(4))) float f4v;     // 16x16 MFMA acc
typedef __attribute__((ext_vector_type(16))) float f16v;   // 32x32 MFMA acc

#define PL   6144            // u32 per plane  (48 sub * 32 b * 4 u32)
#define PL64 3072            // u64 per plane
#define PAR  12288           // u32 per parity (2 planes)
#define HB2  24576           // u32 per layer  (2 parities)

__device__ __forceinline__ float fast_tanh(float x) {
    x = fminf(9.f, fmaxf(-9.f, x));
    float e = __expf(2.f * x);
    return (e - 1.f) / (e + 1.f);
}
__device__ __forceinline__ float sigmoidf(float x) {
    return 1.f / (1.f + __expf(-x));
}
__device__ __forceinline__ bf16u f2bf(float f) {
    uint32 u = __float_as_uint(f);
    u += 0x7fffu + ((u >> 16) & 1u);
    return (bf16u)(u >> 16);
}
__device__ __forceinline__ float bf2f(bf16u u) {
    return __uint_as_float(((uint32)u) << 16);
}
__device__ __forceinline__ uint32 pack2bf(float lo, float hi) {
    return (uint32)f2bf(lo) | ((uint32)f2bf(hi) << 16);
}
__device__ __forceinline__ float bflo(uint32 p) { return __uint_as_float(p << 16); }
__device__ __forceinline__ float bfhi(uint32 p) { return __uint_as_float(p & 0xffff0000u); }

// 16-B A-fragment load straight from the dense broadcast buffer to VGPRs.
// Agent-scope relaxed atomics -> bypass stale L1/L2, hit LLC.
__device__ __forceinline__ s8v ldfrag(const u64* p) {
    union { u64 q[2]; s8v v; } u;
    u.q[0] = __hip_atomic_load(p,     __ATOMIC_RELAXED, __HIP_MEMORY_SCOPE_AGENT);
    u.q[1] = __hip_atomic_load(p + 1, __ATOMIC_RELAXED, __HIP_MEMORY_SCOPE_AGENT);
    return u.v;
}

// ---------------------------------------------------------------------------
// Embedding + context projection -> inp [rt=t*32+b][256] bf16 (emb || ctx)
// ---------------------------------------------------------------------------
__global__ void __launch_bounds__(128) embed_ctx_kernel(
    const int* __restrict__ x, const float* __restrict__ ctx,
    const float* __restrict__ emb, const float* __restrict__ ctxW,
    const float* __restrict__ ctxb, bf16u* __restrict__ inp)
{
    const int r0 = blockIdx.x * 16;
    const int tid = threadIdx.x;
    __shared__ float cs[16][301];
    __shared__ int xs[16];
    for (int i = tid; i < 16 * 300; i += 128) {
        int row = i / 300, k = i - row * 300;
        int rt = r0 + row, b = rt & 31, t = rt >> 5;
        cs[row][k] = ctx[((size_t)b * 1024 + t) * 300 + k];
    }
    if (tid < 16) {
        int rt = r0 + tid;
        xs[tid] = x[(rt & 31) * 1024 + (rt >> 5)];
    }
    __syncthreads();
    float acc[16];
    #pragma unroll
    for (int row = 0; row < 16; ++row) acc[row] = 0.f;
    for (int k = 0; k < 300; ++k) {
        float w = ctxW[tid * 300 + k];
        #pragma unroll
        for (int row = 0; row < 16; ++row) acc[row] = fmaf(w, cs[row][k], acc[row]);
    }
    float bb = ctxb[tid];
    for (int row = 0; row < 16; ++row) {
        size_t base = (size_t)(r0 + row) * 256;
        inp[base + tid]       = f2bf(emb[xs[row] * 128 + tid]);
        inp[base + 128 + tid] = f2bf(acc[row] + bb);
    }
}

// ---------------------------------------------------------------------------
// MFMA GEMM: C[M,N] = A[M,K](bf16) @ W[N,K]^T(f32, split hi/lo bf16)
// A split at K0 between A0/A1. abm=1: A0 is block-major [t][48][32][4u32]
// (16-B chunk s=(k>>3) covers 8 consecutive dims -> same frag granularity).
// mode 1: bf16 out; 2: bf16+tanh; 3: f32 out, row rt->(b*1024+t) (logits).
// BM=BN=64, BK=32.
// ---------------------------------------------------------------------------
__global__ void __launch_bounds__(256) gemm_kernel(
    const bf16u* __restrict__ A0, const bf16u* __restrict__ A1, int K0,
    const float* __restrict__ W, const float* __restrict__ bias1,
    void* __restrict__ Cout, int M, int N, int K, int mode, int abm)
{
    __shared__ bf16u As[64][40];
    __shared__ bf16u Whi[64][40];
    __shared__ bf16u Wlo[64][40];
    const int tid = threadIdx.x;
    const int bn = blockIdx.x * 64, bm = blockIdx.y * 64;
    const int wave = tid >> 6, lane = tid & 63;
    const int wm = wave >> 1, wn = wave & 1;
    const int ncol = lane & 15, quad = lane >> 4;
    const int lr = tid >> 2, lk = (tid & 3) * 8;

    f4v acc[2][2];
    #pragma unroll
    for (int i = 0; i < 2; ++i)
        #pragma unroll
        for (int j = 0; j < 2; ++j) acc[i][j] = (f4v){0.f, 0.f, 0.f, 0.f};

    const int wrow = bn + lr;
    for (int k0 = 0; k0 < K; k0 += 32) {
        uint4 av;
        if (k0 < K0) {
            if (abm) {
                int rt = bm + lr, tt = rt >> 5, bb = rt & 31;
                av = *(const uint4*)((const uint32*)A0 + (size_t)tt * 6144
                        + (size_t)(((k0 + lk) >> 3) * 32 + bb) * 4);
            } else {
                av = *(const uint4*)(A0 + (size_t)(bm + lr) * K0 + k0 + lk);
            }
        } else {
            av = *(const uint4*)(A1 + (size_t)(bm + lr) * (K - K0) + (k0 - K0) + lk);
        }
        float4 w0 = make_float4(0.f, 0.f, 0.f, 0.f), w1 = w0;
        if (wrow < N) {
            const float* wp = W + (size_t)wrow * K + k0 + lk;
            w0 = *(const float4*)wp;
            w1 = *(const float4*)(wp + 4);
        }
        __syncthreads();
        *(uint4*)&As[lr][lk] = av;
        {
            bf16u h[8], l[8];
            float wf[8] = {w0.x, w0.y, w0.z, w0.w, w1.x, w1.y, w1.z, w1.w};
            #pragma unroll
            for (int j = 0; j < 8; ++j) {
                h[j] = f2bf(wf[j]);
                l[j] = f2bf(wf[j] - bf2f(h[j]));
            }
            #pragma unroll
            for (int j = 0; j < 8; ++j) Whi[lr][lk + j] = h[j];
            #pragma unroll
            for (int j = 0; j < 8; ++j) Wlo[lr][lk + j] = l[j];
        }
        __syncthreads();
        s8v aF[2], bH[2], bL[2];
        #pragma unroll
        for (int mt = 0; mt < 2; ++mt)
            aF[mt] = *(const s8v*)&As[wm * 32 + mt * 16 + ncol][quad * 8];
        #pragma unroll
        for (int nt = 0; nt < 2; ++nt) {
            bH[nt] = *(const s8v*)&Whi[wn * 32 + nt * 16 + ncol][quad * 8];
            bL[nt] = *(const s8v*)&Wlo[wn * 32 + nt * 16 + ncol][quad * 8];
        }
        #pragma unroll
        for (int mt = 0; mt < 2; ++mt)
            #pragma unroll
            for (int nt = 0; nt < 2; ++nt) {
                acc[mt][nt] = __builtin_amdgcn_mfma_f32_16x16x32_bf16(
                    aF[mt], bH[nt], acc[mt][nt], 0, 0, 0);
                acc[mt][nt] = __builtin_amdgcn_mfma_f32_16x16x32_bf16(
                    aF[mt], bL[nt], acc[mt][nt], 0, 0, 0);
            }
    }

    #pragma unroll
    for (int nt = 0; nt < 2; ++nt) {
        const int col = bn + wn * 32 + nt * 16 + ncol;
        if (col >= N) continue;
        float bb = bias1 ? bias1[col] : 0.f;
        #pragma unroll
        for (int mt = 0; mt < 2; ++mt) {
            const int rowb = bm + wm * 32 + mt * 16 + quad * 4;
            if (mode == 3) {
                #pragma unroll
                for (int r = 0; r < 4; ++r) {
                    int row = rowb + r;
                    int b = row & 31, t = row >> 5;
                    ((float*)Cout)[((size_t)b * 1024 + t) * (size_t)N + col] =
                        acc[mt][nt][r] + bb;
                }
            } else {
                #pragma unroll
                for (int r = 0; r < 4; ++r) {
                    float v = acc[mt][nt][r] + bb;
                    if (mode == 2) v = fast_tanh(v);
                    ((bf16u*)Cout)[(size_t)(rowb + r) * N + col] = f2bf(v);
                }
            }
        }
    }
}

// ---------------------------------------------------------------------------
// Split barrier (round-7). Entry (strong, upward): post own flag, wait
// {l-1, l} >= v — covers both RAW hazards (producer y, own-layer h).
// The l+1 WAR wait (our round-r h-store overwrites the parity l+1 read in
// its round r-1; it posts flag r+1 at its end) is DEFERRED to mid-round
// (wait_down), just before the cell-update stores — so loads+MFMA overlap
// downstream stragglers. Flags stay one per 128-B line (rounds 3/4 lesson:
// packed sync lines funnel traffic through few LLC slices, +2us/round).
// Deadlock-free: upward waits depend only on upward progress, downward
// waits terminate at l=3 (no wait_down); offsets are one round apart.
// __syncthreads() before the flag store drains vmcnt -> prior agent-scope
// stores are at the LLC coherence point before the flag becomes visible.
// ---------------------------------------------------------------------------
__device__ __forceinline__ void post_and_wait_up(uint32* flags, uint32 v,
                                                 int tid, int l, int bid) {
    __syncthreads();
    if (tid == 0)
        __hip_atomic_store(&flags[bid * 32], v, __ATOMIC_RELAXED, __HIP_MEMORY_SCOPE_AGENT);
    const int lo = (l > 0) ? (l - 1) * 48 : 0;
    const int nf = ((l > 0) ? 2 : 1) * 48;
    if (tid < nf) {
        while (__hip_atomic_load(&flags[(lo + tid) * 32], __ATOMIC_RELAXED,
                                 __HIP_MEMORY_SCOPE_AGENT) < v)
            __builtin_amdgcn_s_sleep(1);
    }
    __syncthreads();
}
__device__ __forceinline__ void wait_down(uint32* flags, uint32 v,
                                          int tid, int l) {
    if (l < 3 && tid < 48) {
        while (__hip_atomic_load(&flags[((l + 1) * 48 + tid) * 32], __ATOMIC_RELAXED,
                                 __HIP_MEMORY_SCOPE_AGENT) < v)
            __builtin_amdgcn_s_sleep(1);
    }
    __syncthreads();
}

// ---------------------------------------------------------------------------
// Layer-wavefront LSTM: 4 layers x 1024 steps, ONE launch, 1027 rounds.
// 192 blocks = 4 layers x 48 sub-blocks x 8 hidden dims.
// Gate MFMAs are 32x32x16, K-split across the 4 waves (each A-fragment
// loaded exactly once per block). Partial tiles -> 4 LDS slabs summed by
// update threads. h broadcast: BLOCK-MAJOR DENSE
// [layer][parity][plane][sub][b][4u32]; A-frag (kt16,khalf,row) = 16 B at
// u64 index ((kt16*2+khalf)*32+row)*2. Layer-3 y3 also block-major;
// consumed directly by gemm(abm)/attn — no transpose kernel.
// ---------------------------------------------------------------------------
__global__ void __launch_bounds__(256, 1) lstm_wave_kernel(
    const bf16u* __restrict__ inp,   // [t*32+b][256] bf16
    const float* __restrict__ Wih0,  // [1536][256]
    const float* __restrict__ WihR,  // [3][1536][384]
    const float* __restrict__ Whh,   // [4][1536][384]
    const float* __restrict__ bih, const float* __restrict__ bhh,
    const float* __restrict__ h_in, const float* __restrict__ c_in,
    uint32* __restrict__ y3bm,       // [1024][48][32][4] u32 (hi plane only)
    uint32* __restrict__ hbuf,       // [4][2][2][48][32][4] u32
    uint32* __restrict__ flags,      // 192 flags, 128-B spaced
    float* __restrict__ hs_out, float* __restrict__ cs_out)
{
    extern __shared__ char sm[];
    const int tid = threadIdx.x, bid = blockIdx.x;
    const int l = bid / 48, sub = bid - l * 48;
    const int j0 = sub * 8;
    const int wave = tid >> 6, lane = tid & 63;
    const int row32 = lane & 31;              // A row (batch) / B row (gate)
    const int khalf = lane >> 5;              // k-half within a 16-chunk
    const int n = row32;                      // local gate-row for B/D col

    const int Kx = l ? 384 : 256;
    const int WSTR = l ? 392 : 264;           // padded bf16 stride
    const int wbytes = 2 * 32 * WSTR * 2;     // Wih planes bytes
    bf16u* wlds  = (bf16u*)sm;
    float* gates = (float*)(sm + wbytes);     // 4 slabs x 1056 f32 = 16896 B

    const float* WhhL = Whh + (size_t)l * 1536 * 384;
    const float* WihL = l ? (WihR + (size_t)(l - 1) * 1536 * 384) : Wih0;
    const float* bihL = bih + l * 1536;
    const float* bhhL = bhh + l * 1536;
    uint32* hbL = hbuf + (size_t)l * HB2;
    uint32* ybL = l ? (hbuf + (size_t)(l - 1) * HB2) : nullptr;

    const int h0c = wave * 6;                 // this wave's h/y k16-chunks
    const int x0c = wave * 4;                 // l0 x k16-chunks

    // ---- Whh B-frags in registers (hi/lo): rows = ALL 32 local gates,
    //      k = this wave's 6 chunks x khalf ----
    s8v Bh6[6], Bl6[6];
    {
        const int wrow = (n >> 3) * 384 + j0 + (n & 7);
        #pragma unroll
        for (int i = 0; i < 6; ++i) {
            const float* wp = WhhL + (size_t)wrow * 384 + (h0c + i) * 16 + khalf * 8;
            s8v hi, lo;
            #pragma unroll
            for (int j = 0; j < 8; ++j) {
                float w = wp[j];
                bf16u wh = f2bf(w);
                bf16u wl = f2bf(w - bf2f(wh));
                hi[j] = (short)wh; lo[j] = (short)wl;
            }
            Bh6[i] = hi; Bl6[i] = lo;
        }
    }
    // ---- Wih slice into LDS (hi/lo planes) ----
    for (int r2 = 0; r2 < 32; ++r2) {
        int rg = (r2 >> 3) * 384 + j0 + (r2 & 7);
        for (int k = tid; k < Kx; k += 256) {
            float w = WihL[(size_t)rg * Kx + k];
            bf16u wh = f2bf(w);
            wlds[r2 * WSTR + k] = wh;
            wlds[32 * WSTR + r2 * WSTR + k] = f2bf(w - bf2f(wh));
        }
    }

    // update role: tid<128 owns (batch ub, dim pair jg0, jg0+1)
    const int ub = tid & 31, jp = tid >> 5;          // jp 0..3 for tid<128
    const int jg0 = j0 + 2 * jp;
    const int wbase = (sub * 32 + ub) * 4 + jp;      // dense u32 index
    float c0r = 0.f, c1r = 0.f, h0l = 0.f, h1l = 0.f;
    float bI0 = 0, bF0 = 0, bG0 = 0, bO0 = 0, bI1 = 0, bF1 = 0, bG1 = 0, bO1 = 0;

    if (tid < 128) {
        bI0 = bihL[jg0] + bhhL[jg0];
        bF0 = bihL[384 + jg0] + bhhL[384 + jg0];
        bG0 = bihL[768 + jg0] + bhhL[768 + jg0];
        bO0 = bihL[1152 + jg0] + bhhL[1152 + jg0];
        bI1 = bihL[jg0 + 1] + bhhL[jg0 + 1];
        bF1 = bihL[384 + jg0 + 1] + bhhL[384 + jg0 + 1];
        bG1 = bihL[768 + jg0 + 1] + bhhL[768 + jg0 + 1];
        bO1 = bihL[1152 + jg0 + 1] + bhhL[1152 + jg0 + 1];
        float ha = h_in[(size_t)l * 12288 + ub * 384 + jg0];
        float hb = h_in[(size_t)l * 12288 + ub * 384 + jg0 + 1];
        bf16u ha_h = f2bf(ha); bf16u ha_l = f2bf(ha - bf2f(ha_h));
        bf16u hb_h = f2bf(hb); bf16u hb_l = f2bf(hb - bf2f(hb_h));
        __hip_atomic_store(&hbL[wbase],
                           (uint32)ha_h | ((uint32)hb_h << 16),
                           __ATOMIC_RELAXED, __HIP_MEMORY_SCOPE_AGENT);
        __hip_atomic_store(&hbL[PL + wbase],
                           (uint32)ha_l | ((uint32)hb_l << 16),
                           __ATOMIC_RELAXED, __HIP_MEMORY_SCOPE_AGENT);
        c0r = c_in[(size_t)l * 12288 + ub * 384 + jg0];
        c1r = c_in[(size_t)l * 12288 + ub * 384 + jg0 + 1];
    }
    post_and_wait_up(flags, 1u, tid, l, bid);

    for (int r = 0; r < 1027; ++r) {
        const int t = r - l;
        if ((unsigned)t < 1024u) {
            const u64* hB = (const u64*)(hbL + (t & 1) * PAR);
            uint32* hW = hbL + ((t + 1) & 1) * PAR;

            f16v cHH = {0.f,0.f,0.f,0.f,0.f,0.f,0.f,0.f,
                        0.f,0.f,0.f,0.f,0.f,0.f,0.f,0.f};
            f16v cLH = cHH, cHL = cHH;

            // ---- h @ Whh^T : this wave's 6 k16-chunks, frags loaded once ----
            #pragma unroll
            for (int i = 0; i < 6; ++i) {
                const int kt = h0c + i;
                const int co = ((kt * 2 + khalf) * 32 + row32) * 2;
                s8v Ah = ldfrag(hB + co);
                s8v Al = ldfrag(hB + PL64 + co);
                cHH = __builtin_amdgcn_mfma_f32_32x32x16_bf16(Ah, Bh6[i], cHH, 0, 0, 0);
                cLH = __builtin_amdgcn_mfma_f32_32x32x16_bf16(Al, Bh6[i], cLH, 0, 0, 0);
                cHL = __builtin_amdgcn_mfma_f32_32x32x16_bf16(Ah, Bl6[i], cHL, 0, 0, 0);
            }
            if (l) {
                const u64* yB = (const u64*)(ybL + ((t + 1) & 1) * PAR);
                #pragma unroll
                for (int i = 0; i < 6; ++i) {
                    const int kt = h0c + i;
                    const int co = ((kt * 2 + khalf) * 32 + row32) * 2;
                    s8v Ayh = ldfrag(yB + co);
                    s8v Ayl = ldfrag(yB + PL64 + co);
                    s8v Bxh = *(const s8v*)&wlds[n * 392 + kt * 16 + khalf * 8];
                    s8v Bxl = *(const s8v*)&wlds[32 * 392 + n * 392 + kt * 16 + khalf * 8];
                    cHH = __builtin_amdgcn_mfma_f32_32x32x16_bf16(Ayh, Bxh, cHH, 0, 0, 0);
                    cLH = __builtin_amdgcn_mfma_f32_32x32x16_bf16(Ayl, Bxh, cLH, 0, 0, 0);
                    cHL = __builtin_amdgcn_mfma_f32_32x32x16_bf16(Ayh, Bxl, cHL, 0, 0, 0);
                }
            } else {
                const uint4* irow = (const uint4*)(inp + ((size_t)t * 32 + row32) * 256);
                #pragma unroll
                for (int i = 0; i < 4; ++i) {
                    const int kt = x0c + i;
                    union { uint4 u; s8v v; } cv;
                    cv.u = irow[kt * 2 + khalf];
                    s8v Bxh = *(const s8v*)&wlds[n * 264 + kt * 16 + khalf * 8];
                    s8v Bxl = *(const s8v*)&wlds[32 * 264 + n * 264 + kt * 16 + khalf * 8];
                    cHH = __builtin_amdgcn_mfma_f32_32x32x16_bf16(cv.v, Bxh, cHH, 0, 0, 0);
                    cHL = __builtin_amdgcn_mfma_f32_32x32x16_bf16(cv.v, Bxl, cHL, 0, 0, 0);
                }
            }
            // ---- partial tile -> this wave's LDS slab ----
            {
                float* ps = gates + wave * 1056;
                #pragma unroll
                for (int reg = 0; reg < 16; ++reg) {
                    const int brow = (reg & 3) + 8 * (reg >> 2) + 4 * khalf;
                    ps[n * 33 + brow] = cHH[reg] + cLH[reg] + cHL[reg];
                }
            }
            __syncthreads();

            // ---- WAR guard (deferred): l+1 finished round r-1 (it read the
            // parity we are about to overwrite; posts flag r+1 at its end) ----
            wait_down(flags, (uint32)(r + 1), tid, l);

            // ---- cell update: tid<128, 2 dims each; sum 4 K-partials ----
            if (tid < 128) {
                const int jj0 = 2 * jp, jj1 = 2 * jp + 1;
                #define GS(g) (gates[(g) * 33 + ub] + gates[1056 + (g) * 33 + ub] + \
                               gates[2112 + (g) * 33 + ub] + gates[3168 + (g) * 33 + ub])
                float pi0 = GS(jj0)      + bI0;
                float pf0 = GS(8 + jj0)  + bF0;
                float pg0 = GS(16 + jj0) + bG0;
                float po0 = GS(24 + jj0) + bO0;
                float pi1 = GS(jj1)      + bI1;
                float pf1 = GS(8 + jj1)  + bF1;
                float pg1 = GS(16 + jj1) + bG1;
                float po1 = GS(24 + jj1) + bO1;
                #undef GS
                c0r = sigmoidf(pf0) * c0r + sigmoidf(pi0) * fast_tanh(pg0);
                c1r = sigmoidf(pf1) * c1r + sigmoidf(pi1) * fast_tanh(pg1);
                float hv0 = sigmoidf(po0) * fast_tanh(c0r);
                float hv1 = sigmoidf(po1) * fast_tanh(c1r);
                h0l = hv0; h1l = hv1;
                bf16u h0h = f2bf(hv0); bf16u h0lo = f2bf(hv0 - bf2f(h0h));
                bf16u h1h = f2bf(hv1); bf16u h1lo = f2bf(hv1 - bf2f(h1h));
                uint32 hiw = (uint32)h0h | ((uint32)h1h << 16);
                uint32 low = (uint32)h0lo | ((uint32)h1lo << 16);
                __hip_atomic_store(&hW[wbase], hiw,
                                   __ATOMIC_RELAXED, __HIP_MEMORY_SCOPE_AGENT);
                __hip_atomic_store(&hW[PL + wbase], low,
                                   __ATOMIC_RELAXED, __HIP_MEMORY_SCOPE_AGENT);
                if (l == 3)
                    y3bm[(size_t)t * 6144 + wbase] = hiw;   // dense full lines
            }
        }
        post_and_wait_up(flags, (uint32)(r + 2), tid, l, bid);
    }

    if (tid < 128) {
        hs_out[(size_t)l * 12288 + ub * 384 + jg0]     = h0l;
        hs_out[(size_t)l * 12288 + ub * 384 + jg0 + 1] = h1l;
        cs_out[(size_t)l * 12288 + ub * 384 + jg0]     = c0r;
        cs_out[(size_t)l * 12288 + ub * 384 + jg0 + 1] = c1r;
    }
}

// ---------------------------------------------------------------------------
// Causal flash attention; Q and V read DIRECTLY from block-major y3bm
// (u32 for dim-pair dp of (t,b) = y3bm[t*6144 + (dp>>2)*128 + b*4 + (dp&3)]).
// K from standard-layout keys.
// ---------------------------------------------------------------------------
__global__ void __launch_bounds__(256) attn_kernel(
    const uint32* __restrict__ y3, const bf16u* __restrict__ keys,
    bf16u* __restrict__ ctxv)
{
    const int b = blockIdx.y;
    const int q0 = blockIdx.x * 32;
    const int tid = threadIdx.x;
    __shared__ uint32 Qs[32][194];
    __shared__ uint32 Ks[16][194];
    __shared__ uint32 Vs[16][192];
    __shared__ float Ss[32][16];
    __shared__ float m_s[32], l_s[32], alpha_s[32];

    for (int i = tid; i < 32 * 192; i += 256) {
        int q = i / 192, dp = i - q * 192;
        Qs[q][dp] = y3[(size_t)(q0 + q) * 6144 + (dp >> 2) * 128 + b * 4 + (dp & 3)];
    }
    if (tid < 32) { m_s[tid] = -3e38f; l_s[tid] = 0.f; }

    const int qo = tid >> 3, dg = tid & 7;
    float O[48];
    #pragma unroll
    for (int d = 0; d < 48; ++d) O[d] = 0.f;

    const int nkt = (q0 + 32) >> 4;
    for (int kt = 0; kt < nkt; ++kt) {
        const int k0 = kt * 16;
        __syncthreads();
        for (int i = tid; i < 16 * 192; i += 256) {
            int kk = i / 192, dp = i - kk * 192;
            size_t rt = (size_t)(k0 + kk) * 32 + b;
            Ks[kk][dp] = ((const uint32*)(keys + rt * 384))[dp];
            Vs[kk][dp] = y3[(size_t)(k0 + kk) * 6144 + (dp >> 2) * 128 + b * 4 + (dp & 3)];
        }
        __syncthreads();
        #pragma unroll
        for (int pp = 0; pp < 2; ++pp) {
            int p = tid + pp * 256;
            int q = p >> 4, k = p & 15;
            const uint32* qrow = Qs[q];
            const uint32* krow = Ks[k];
            float acc = 0.f;
            for (int dp = 0; dp < 192; ++dp) {
                uint32 qa = qrow[dp], ka = krow[dp];
                acc = fmaf(bflo(qa), bflo(ka), acc);
                acc = fmaf(bfhi(qa), bfhi(ka), acc);
            }
            acc *= 0.051031036307982884f;    // 1/sqrt(384)
            Ss[q][k] = ((k0 + k) <= (q0 + q)) ? acc : -1e30f;
        }
        __syncthreads();
        if (tid < 32) {
            int q = tid;
            float mt = m_s[q];
            #pragma unroll
            for (int k = 0; k < 16; ++k) mt = fmaxf(mt, Ss[q][k]);
            float alpha = __expf(m_s[q] - mt);
            float l = l_s[q] * alpha;
            #pragma unroll
            for (int k = 0; k < 16; ++k) {
                float pv = __expf(Ss[q][k] - mt);
                Ss[q][k] = pv;
                l += pv;
            }
            m_s[q] = mt; l_s[q] = l; alpha_s[q] = alpha;
        }
        __syncthreads();
        {
            float al = alpha_s[qo];
            #pragma unroll
            for (int d = 0; d < 48; ++d) O[d] *= al;
            for (int k = 0; k < 16; ++k) {
                float pv = Ss[qo][k];
                const uint32* vrow = Vs[k] + dg * 24;
                #pragma unroll
                for (int dp = 0; dp < 24; ++dp) {
                    uint32 va = vrow[dp];
                    O[2 * dp]     = fmaf(pv, bflo(va), O[2 * dp]);
                    O[2 * dp + 1] = fmaf(pv, bfhi(va), O[2 * dp + 1]);
                }
            }
        }
    }
    float inv = 1.f / l_s[qo];
    uint32* dst = (uint32*)(ctxv + ((size_t)(q0 + qo) * 32 + b) * 384) + dg * 24;
    #pragma unroll
    for (int dp = 0; dp < 24; ++dp)
        dst[dp] = pack2bf(O[2 * dp] * inv, O[2 * dp + 1] * inv);
}

// ---------------------------------------------------------------------------
extern "C" void kernel_launch(void* const* d_in, const int* in_sizes, int n_in,
                              void* d_out, int out_size, void* d_ws, size_t ws_size,
                              hipStream_t stream) {
    (void)in_sizes; (void)n_in; (void)out_size; (void)ws_size;
    const int*   x        = (const int*)d_in[0];
    const float* context  = (const float*)d_in[1];
    const float* h_in     = (const float*)d_in[2];
    const float* c_in     = (const float*)d_in[3];
    const float* emb      = (const float*)d_in[4];
    const float* ctx_W    = (const float*)d_in[5];
    const float* ctx_b    = (const float*)d_in[6];
    const float* Wih0     = (const float*)d_in[7];
    const float* Wih_rest = (const float*)d_in[8];
    const float* Whh      = (const float*)d_in[9];
    const float* bih      = (const float*)d_in[10];
    const float* bhh      = (const float*)d_in[11];
    const float* Wa       = (const float*)d_in[12];
    const float* comb_W   = (const float*)d_in[13];
    const float* comb_b   = (const float*)d_in[14];
    const float* fc_W     = (const float*)d_in[15];
    const float* fc_b     = (const float*)d_in[16];
    float* out = (float*)d_out;

    // ---- workspace layout, 75.92 MB peak (transpose fused away) ----
    char* wsb = (char*)d_ws;
    uint32* flags = (uint32*)(wsb + 0);               //  32 KB (192 lines)
    uint32* hbuf  = (uint32*)(wsb + 32768);           // 393 KB dense block-major
    uint32* y3bm  = (uint32*)(wsb + 425984);          // 25.17 MB [1024][6144]u32
    bf16u*  ctxvu = (bf16u*)(wsb + 25591808ull);      // 25.17 MB (attn -> comb)
    bf16u*  inp   = (bf16u*)(wsb + 50757632ull);      // 16.78 MB (lstm only)
    bf16u*  keysu = (bf16u*)(wsb + 50757632ull);      // reuse (inp dead post-lstm)
    bf16u*  combu = (bf16u*)(wsb + 50757632ull);      // reuse (keys dead post-attn)

    hipMemsetAsync(d_ws, 0, 32768, stream);           // zero flags

    static int smem_set = 0;
    if (!smem_set) {
        hipFuncSetAttribute((const void*)lstm_wave_kernel,
                            hipFuncAttributeMaxDynamicSharedMemorySize, 67072);
        smem_set = 1;
    }

    embed_ctx_kernel<<<2048, 128, 0, stream>>>(x, context, emb, ctx_W, ctx_b, inp);

    const size_t HS_OFF = (size_t)32768 * 100;
    // dynamic LDS: Wih planes (max 50176 B at l>0) + 4 gate slabs 16896 B
    lstm_wave_kernel<<<192, 256, 67072, stream>>>(
        inp, Wih0, Wih_rest, Whh, bih, bhh, h_in, c_in,
        y3bm, hbuf, flags, out + HS_OFF, out + HS_OFF + 49152);

    // keys = y3 @ Wa^T  (A read block-major)
    gemm_kernel<<<dim3(6, 512), 256, 0, stream>>>(
        (const bf16u*)y3bm, nullptr, 384, Wa, nullptr, keysu, 32768, 384, 384, 1, 1);
    // ctx_vec (flash attention; Q/V block-major)
    attn_kernel<<<dim3(32, 32), 256, 0, stream>>>(y3bm, keysu, ctxvu);
    // combined = tanh([y3, ctx] @ comb_W^T + b)  (A0 block-major, A1 standard)
    gemm_kernel<<<dim3(6, 512), 256, 0, stream>>>(
        (const bf16u*)y3bm, ctxvu, 384, comb_W, comb_b, combu, 32768, 384, 768, 2, 1);
    // logits = combined @ fc_W^T + fc_b  -> d_out permuted [b][t][100]
    gemm_kernel<<<dim3(2, 512), 256, 0, stream>>>(
        combu, nullptr, 384, fc_W, fc_b, out, 32768, 100, 384, 3, 0);
}

// Round 9
// 6345.334 us; speedup vs baseline: 1.1720x; 1.1720x over previous
//
#include <hip/hip_runtime.h>

typedef unsigned int  uint32;
typedef unsigned long long u64;
typedef unsigned short bf16u;
typedef __attribute__((ext_vector_type(8))) short s8v;     // 8 bf16 (4 VGPRs)
typedef __attribute__((ext_vector_type(4))) float f4v;     // 16x16 MFMA acc
typedef __attribute__((ext_vector_type(16))) float f16v;   // 32x32 MFMA acc

#define PL   6144            // u32 per plane  (48 sub * 32 b * 4 u32)
#define PL64 3072            // u64 per plane
#define PAR  12288           // u32 per parity (2 planes)
#define HB2  24576           // u32 per layer  (2 parities)

__device__ __forceinline__ float fast_tanh(float x) {
    x = fminf(9.f, fmaxf(-9.f, x));
    float e = __expf(2.f * x);
    return (e - 1.f) / (e + 1.f);
}
__device__ __forceinline__ float sigmoidf(float x) {
    return 1.f / (1.f + __expf(-x));
}
__device__ __forceinline__ bf16u f2bf(float f) {
    uint32 u = __float_as_uint(f);
    u += 0x7fffu + ((u >> 16) & 1u);
    return (bf16u)(u >> 16);
}
__device__ __forceinline__ float bf2f(bf16u u) {
    return __uint_as_float(((uint32)u) << 16);
}
__device__ __forceinline__ uint32 pack2bf(float lo, float hi) {
    return (uint32)f2bf(lo) | ((uint32)f2bf(hi) << 16);
}
__device__ __forceinline__ float bflo(uint32 p) { return __uint_as_float(p << 16); }
__device__ __forceinline__ float bfhi(uint32 p) { return __uint_as_float(p & 0xffff0000u); }

// 16-B A-fragment load straight from the dense broadcast buffer to VGPRs.
// Agent-scope relaxed atomics -> bypass stale L1/L2, hit LLC.
__device__ __forceinline__ s8v ldfrag(const u64* p) {
    union { u64 q[2]; s8v v; } u;
    u.q[0] = __hip_atomic_load(p,     __ATOMIC_RELAXED, __HIP_MEMORY_SCOPE_AGENT);
    u.q[1] = __hip_atomic_load(p + 1, __ATOMIC_RELAXED, __HIP_MEMORY_SCOPE_AGENT);
    return u.v;
}

// ---------------------------------------------------------------------------
// Embedding + context projection -> inp [rt=t*32+b][256] bf16 (emb || ctx)
// ---------------------------------------------------------------------------
__global__ void __launch_bounds__(128) embed_ctx_kernel(
    const int* __restrict__ x, const float* __restrict__ ctx,
    const float* __restrict__ emb, const float* __restrict__ ctxW,
    const float* __restrict__ ctxb, bf16u* __restrict__ inp)
{
    const int r0 = blockIdx.x * 16;
    const int tid = threadIdx.x;
    __shared__ float cs[16][301];
    __shared__ int xs[16];
    for (int i = tid; i < 16 * 300; i += 128) {
        int row = i / 300, k = i - row * 300;
        int rt = r0 + row, b = rt & 31, t = rt >> 5;
        cs[row][k] = ctx[((size_t)b * 1024 + t) * 300 + k];
    }
    if (tid < 16) {
        int rt = r0 + tid;
        xs[tid] = x[(rt & 31) * 1024 + (rt >> 5)];
    }
    __syncthreads();
    float acc[16];
    #pragma unroll
    for (int row = 0; row < 16; ++row) acc[row] = 0.f;
    for (int k = 0; k < 300; ++k) {
        float w = ctxW[tid * 300 + k];
        #pragma unroll
        for (int row = 0; row < 16; ++row) acc[row] = fmaf(w, cs[row][k], acc[row]);
    }
    float bb = ctxb[tid];
    for (int row = 0; row < 16; ++row) {
        size_t base = (size_t)(r0 + row) * 256;
        inp[base + tid]       = f2bf(emb[xs[row] * 128 + tid]);
        inp[base + 128 + tid] = f2bf(acc[row] + bb);
    }
}

// ---------------------------------------------------------------------------
// MFMA GEMM: C[M,N] = A[M,K](bf16) @ W[N,K]^T(f32, split hi/lo bf16)
// A split at K0 between A0/A1. mode 1: bf16 out; 2: bf16+tanh;
// 3: f32 out, row rt->(b*1024+t) (logits). BM=BN=64, BK=32.
// ---------------------------------------------------------------------------
__global__ void __launch_bounds__(256) gemm_kernel(
    const bf16u* __restrict__ A0, const bf16u* __restrict__ A1, int K0,
    const float* __restrict__ W, const float* __restrict__ bias1,
    void* __restrict__ Cout, int M, int N, int K, int mode)
{
    __shared__ bf16u As[64][40];
    __shared__ bf16u Whi[64][40];
    __shared__ bf16u Wlo[64][40];
    const int tid = threadIdx.x;
    const int bn = blockIdx.x * 64, bm = blockIdx.y * 64;
    const int wave = tid >> 6, lane = tid & 63;
    const int wm = wave >> 1, wn = wave & 1;
    const int ncol = lane & 15, quad = lane >> 4;
    const int lr = tid >> 2, lk = (tid & 3) * 8;

    f4v acc[2][2];
    #pragma unroll
    for (int i = 0; i < 2; ++i)
        #pragma unroll
        for (int j = 0; j < 2; ++j) acc[i][j] = (f4v){0.f, 0.f, 0.f, 0.f};

    const int wrow = bn + lr;
    for (int k0 = 0; k0 < K; k0 += 32) {
        const bf16u* Ab; int kb, lda;
        if (k0 < K0) { Ab = A0; kb = k0; lda = K0; }
        else         { Ab = A1; kb = k0 - K0; lda = K - K0; }
        uint4 av = *(const uint4*)(Ab + (size_t)(bm + lr) * lda + kb + lk);
        float4 w0 = make_float4(0.f, 0.f, 0.f, 0.f), w1 = w0;
        if (wrow < N) {
            const float* wp = W + (size_t)wrow * K + k0 + lk;
            w0 = *(const float4*)wp;
            w1 = *(const float4*)(wp + 4);
        }
        __syncthreads();
        *(uint4*)&As[lr][lk] = av;
        {
            bf16u h[8], l[8];
            float wf[8] = {w0.x, w0.y, w0.z, w0.w, w1.x, w1.y, w1.z, w1.w};
            #pragma unroll
            for (int j = 0; j < 8; ++j) {
                h[j] = f2bf(wf[j]);
                l[j] = f2bf(wf[j] - bf2f(h[j]));
            }
            #pragma unroll
            for (int j = 0; j < 8; ++j) Whi[lr][lk + j] = h[j];
            #pragma unroll
            for (int j = 0; j < 8; ++j) Wlo[lr][lk + j] = l[j];
        }
        __syncthreads();
        s8v aF[2], bH[2], bL[2];
        #pragma unroll
        for (int mt = 0; mt < 2; ++mt)
            aF[mt] = *(const s8v*)&As[wm * 32 + mt * 16 + ncol][quad * 8];
        #pragma unroll
        for (int nt = 0; nt < 2; ++nt) {
            bH[nt] = *(const s8v*)&Whi[wn * 32 + nt * 16 + ncol][quad * 8];
            bL[nt] = *(const s8v*)&Wlo[wn * 32 + nt * 16 + ncol][quad * 8];
        }
        #pragma unroll
        for (int mt = 0; mt < 2; ++mt)
            #pragma unroll
            for (int nt = 0; nt < 2; ++nt) {
                acc[mt][nt] = __builtin_amdgcn_mfma_f32_16x16x32_bf16(
                    aF[mt], bH[nt], acc[mt][nt], 0, 0, 0);
                acc[mt][nt] = __builtin_amdgcn_mfma_f32_16x16x32_bf16(
                    aF[mt], bL[nt], acc[mt][nt], 0, 0, 0);
            }
    }

    #pragma unroll
    for (int nt = 0; nt < 2; ++nt) {
        const int col = bn + wn * 32 + nt * 16 + ncol;
        if (col >= N) continue;
        float bb = bias1 ? bias1[col] : 0.f;
        #pragma unroll
        for (int mt = 0; mt < 2; ++mt) {
            const int rowb = bm + wm * 32 + mt * 16 + quad * 4;
            if (mode == 3) {
                #pragma unroll
                for (int r = 0; r < 4; ++r) {
                    int row = rowb + r;
                    int b = row & 31, t = row >> 5;
                    ((float*)Cout)[((size_t)b * 1024 + t) * (size_t)N + col] =
                        acc[mt][nt][r] + bb;
                }
            } else {
                #pragma unroll
                for (int r = 0; r < 4; ++r) {
                    float v = acc[mt][nt][r] + bb;
                    if (mode == 2) v = fast_tanh(v);
                    ((bf16u*)Cout)[(size_t)(rowb + r) * N + col] = f2bf(v);
                }
            }
        }
    }
}

// ---------------------------------------------------------------------------
// Scoped flag barrier (round-6 verified): per-block flag on its OWN 128-B
// line (packing sync lines funnels traffic through few LLC slices: +2us/rd).
// Poll only the 3-layer stencil {l-1, l, l+1}.
// ---------------------------------------------------------------------------
__device__ __forceinline__ void scoped_barrier(uint32* flags, uint32 r,
                                               int tid, int l, int bid) {
    __syncthreads();
    if (tid == 0)
        __hip_atomic_store(&flags[bid * 32], r, __ATOMIC_RELAXED, __HIP_MEMORY_SCOPE_AGENT);
    const int lo = (l > 0) ? (l - 1) * 48 : 0;
    const int nf = ((l > 0) + 1 + (l < 3)) * 48;
    if (tid < nf) {
        while (__hip_atomic_load(&flags[(lo + tid) * 32], __ATOMIC_RELAXED,
                                 __HIP_MEMORY_SCOPE_AGENT) < r)
            __builtin_amdgcn_s_sleep(1);
    }
    __syncthreads();
}

// ---------------------------------------------------------------------------
// Layer-wavefront LSTM (round-6 verified): 4 layers x 1024 steps, ONE launch,
// 1027 rounds. 192 blocks = 4 layers x 48 sub-blocks x 8 hidden dims.
// Gate MFMAs are 32x32x16, K-split across the 4 waves (each A-fragment
// loaded exactly once per block). Partial tiles -> 4 LDS slabs summed by
// update threads. h broadcast: BLOCK-MAJOR DENSE
// [layer][parity][plane][sub][b][4u32]; A-frag (kt16,khalf,row) = 16 B at
// u64 index ((kt16*2+khalf)*32+row)*2.
// ---------------------------------------------------------------------------
__global__ void __launch_bounds__(256, 1) lstm_wave_kernel(
    const bf16u* __restrict__ inp,   // [t*32+b][256] bf16
    const float* __restrict__ Wih0,  // [1536][256]
    const float* __restrict__ WihR,  // [3][1536][384]
    const float* __restrict__ Whh,   // [4][1536][384]
    const float* __restrict__ bih, const float* __restrict__ bhh,
    const float* __restrict__ h_in, const float* __restrict__ c_in,
    uint32* __restrict__ y3bm,       // [1024][48][32][4] u32 (hi plane only)
    uint32* __restrict__ hbuf,       // [4][2][2][48][32][4] u32
    uint32* __restrict__ flags,      // 192 flags, 128-B spaced
    float* __restrict__ hs_out, float* __restrict__ cs_out)
{
    extern __shared__ char sm[];
    const int tid = threadIdx.x, bid = blockIdx.x;
    const int l = bid / 48, sub = bid - l * 48;
    const int j0 = sub * 8;
    const int wave = tid >> 6, lane = tid & 63;
    const int row32 = lane & 31;              // A row (batch) / B row (gate)
    const int khalf = lane >> 5;              // k-half within a 16-chunk
    const int n = row32;                      // local gate-row for B/D col

    const int Kx = l ? 384 : 256;
    const int WSTR = l ? 392 : 264;           // padded bf16 stride
    const int wbytes = 2 * 32 * WSTR * 2;     // Wih planes bytes
    bf16u* wlds  = (bf16u*)sm;
    float* gates = (float*)(sm + wbytes);     // 4 slabs x 1056 f32 = 16896 B

    const float* WhhL = Whh + (size_t)l * 1536 * 384;
    const float* WihL = l ? (WihR + (size_t)(l - 1) * 1536 * 384) : Wih0;
    const float* bihL = bih + l * 1536;
    const float* bhhL = bhh + l * 1536;
    uint32* hbL = hbuf + (size_t)l * HB2;
    uint32* ybL = l ? (hbuf + (size_t)(l - 1) * HB2) : nullptr;

    const int h0c = wave * 6;                 // this wave's h/y k16-chunks
    const int x0c = wave * 4;                 // l0 x k16-chunks

    // ---- Whh B-frags in registers (hi/lo): rows = ALL 32 local gates,
    //      k = this wave's 6 chunks x khalf ----
    s8v Bh6[6], Bl6[6];
    {
        const int wrow = (n >> 3) * 384 + j0 + (n & 7);
        #pragma unroll
        for (int i = 0; i < 6; ++i) {
            const float* wp = WhhL + (size_t)wrow * 384 + (h0c + i) * 16 + khalf * 8;
            s8v hi, lo;
            #pragma unroll
            for (int j = 0; j < 8; ++j) {
                float w = wp[j];
                bf16u wh = f2bf(w);
                bf16u wl = f2bf(w - bf2f(wh));
                hi[j] = (short)wh; lo[j] = (short)wl;
            }
            Bh6[i] = hi; Bl6[i] = lo;
        }
    }
    // ---- Wih slice into LDS (hi/lo planes) ----
    for (int r2 = 0; r2 < 32; ++r2) {
        int rg = (r2 >> 3) * 384 + j0 + (r2 & 7);
        for (int k = tid; k < Kx; k += 256) {
            float w = WihL[(size_t)rg * Kx + k];
            bf16u wh = f2bf(w);
            wlds[r2 * WSTR + k] = wh;
            wlds[32 * WSTR + r2 * WSTR + k] = f2bf(w - bf2f(wh));
        }
    }

    // update role: tid<128 owns (batch ub, dim pair jg0, jg0+1)
    const int ub = tid & 31, jp = tid >> 5;          // jp 0..3 for tid<128
    const int jg0 = j0 + 2 * jp;
    const int wbase = (sub * 32 + ub) * 4 + jp;      // dense u32 index
    float c0r = 0.f, c1r = 0.f, h0l = 0.f, h1l = 0.f;
    float bI0 = 0, bF0 = 0, bG0 = 0, bO0 = 0, bI1 = 0, bF1 = 0, bG1 = 0, bO1 = 0;

    if (tid < 128) {
        bI0 = bihL[jg0] + bhhL[jg0];
        bF0 = bihL[384 + jg0] + bhhL[384 + jg0];
        bG0 = bihL[768 + jg0] + bhhL[768 + jg0];
        bO0 = bihL[1152 + jg0] + bhhL[1152 + jg0];
        bI1 = bihL[jg0 + 1] + bhhL[jg0 + 1];
        bF1 = bihL[384 + jg0 + 1] + bhhL[384 + jg0 + 1];
        bG1 = bihL[768 + jg0 + 1] + bhhL[768 + jg0 + 1];
        bO1 = bihL[1152 + jg0 + 1] + bhhL[1152 + jg0 + 1];
        float ha = h_in[(size_t)l * 12288 + ub * 384 + jg0];
        float hb = h_in[(size_t)l * 12288 + ub * 384 + jg0 + 1];
        bf16u ha_h = f2bf(ha); bf16u ha_l = f2bf(ha - bf2f(ha_h));
        bf16u hb_h = f2bf(hb); bf16u hb_l = f2bf(hb - bf2f(hb_h));
        __hip_atomic_store(&hbL[wbase],
                           (uint32)ha_h | ((uint32)hb_h << 16),
                           __ATOMIC_RELAXED, __HIP_MEMORY_SCOPE_AGENT);
        __hip_atomic_store(&hbL[PL + wbase],
                           (uint32)ha_l | ((uint32)hb_l << 16),
                           __ATOMIC_RELAXED, __HIP_MEMORY_SCOPE_AGENT);
        c0r = c_in[(size_t)l * 12288 + ub * 384 + jg0];
        c1r = c_in[(size_t)l * 12288 + ub * 384 + jg0 + 1];
    }
    scoped_barrier(flags, 1u, tid, l, bid);

    for (int r = 0; r < 1027; ++r) {
        const int t = r - l;
        if ((unsigned)t < 1024u) {
            const u64* hB = (const u64*)(hbL + (t & 1) * PAR);
            uint32* hW = hbL + ((t + 1) & 1) * PAR;

            f16v cHH = {0.f,0.f,0.f,0.f,0.f,0.f,0.f,0.f,
                        0.f,0.f,0.f,0.f,0.f,0.f,0.f,0.f};
            f16v cLH = cHH, cHL = cHH;

            // ---- h @ Whh^T : this wave's 6 k16-chunks, frags loaded once ----
            #pragma unroll
            for (int i = 0; i < 6; ++i) {
                const int kt = h0c + i;
                const int co = ((kt * 2 + khalf) * 32 + row32) * 2;
                s8v Ah = ldfrag(hB + co);
                s8v Al = ldfrag(hB + PL64 + co);
                cHH = __builtin_amdgcn_mfma_f32_32x32x16_bf16(Ah, Bh6[i], cHH, 0, 0, 0);
                cLH = __builtin_amdgcn_mfma_f32_32x32x16_bf16(Al, Bh6[i], cLH, 0, 0, 0);
                cHL = __builtin_amdgcn_mfma_f32_32x32x16_bf16(Ah, Bl6[i], cHL, 0, 0, 0);
            }
            if (l) {
                const u64* yB = (const u64*)(ybL + ((t + 1) & 1) * PAR);
                #pragma unroll
                for (int i = 0; i < 6; ++i) {
                    const int kt = h0c + i;
                    const int co = ((kt * 2 + khalf) * 32 + row32) * 2;
                    s8v Ayh = ldfrag(yB + co);
                    s8v Ayl = ldfrag(yB + PL64 + co);
                    s8v Bxh = *(const s8v*)&wlds[n * 392 + kt * 16 + khalf * 8];
                    s8v Bxl = *(const s8v*)&wlds[32 * 392 + n * 392 + kt * 16 + khalf * 8];
                    cHH = __builtin_amdgcn_mfma_f32_32x32x16_bf16(Ayh, Bxh, cHH, 0, 0, 0);
                    cLH = __builtin_amdgcn_mfma_f32_32x32x16_bf16(Ayl, Bxh, cLH, 0, 0, 0);
                    cHL = __builtin_amdgcn_mfma_f32_32x32x16_bf16(Ayh, Bxl, cHL, 0, 0, 0);
                }
            } else {
                const uint4* irow = (const uint4*)(inp + ((size_t)t * 32 + row32) * 256);
                #pragma unroll
                for (int i = 0; i < 4; ++i) {
                    const int kt = x0c + i;
                    union { uint4 u; s8v v; } cv;
                    cv.u = irow[kt * 2 + khalf];
                    s8v Bxh = *(const s8v*)&wlds[n * 264 + kt * 16 + khalf * 8];
                    s8v Bxl = *(const s8v*)&wlds[32 * 264 + n * 264 + kt * 16 + khalf * 8];
                    cHH = __builtin_amdgcn_mfma_f32_32x32x16_bf16(cv.v, Bxh, cHH, 0, 0, 0);
                    cHL = __builtin_amdgcn_mfma_f32_32x32x16_bf16(cv.v, Bxl, cHL, 0, 0, 0);
                }
            }
            // ---- partial tile -> this wave's LDS slab ----
            {
                float* ps = gates + wave * 1056;
                #pragma unroll
                for (int reg = 0; reg < 16; ++reg) {
                    const int brow = (reg & 3) + 8 * (reg >> 2) + 4 * khalf;
                    ps[n * 33 + brow] = cHH[reg] + cLH[reg] + cHL[reg];
                }
            }
            __syncthreads();

            // ---- cell update: tid<128, 2 dims each; sum 4 K-partials ----
            if (tid < 128) {
                const int jj0 = 2 * jp, jj1 = 2 * jp + 1;
                #define GS(g) (gates[(g) * 33 + ub] + gates[1056 + (g) * 33 + ub] + \
                               gates[2112 + (g) * 33 + ub] + gates[3168 + (g) * 33 + ub])
                float pi0 = GS(jj0)      + bI0;
                float pf0 = GS(8 + jj0)  + bF0;
                float pg0 = GS(16 + jj0) + bG0;
                float po0 = GS(24 + jj0) + bO0;
                float pi1 = GS(jj1)      + bI1;
                float pf1 = GS(8 + jj1)  + bF1;
                float pg1 = GS(16 + jj1) + bG1;
                float po1 = GS(24 + jj1) + bO1;
                #undef GS
                c0r = sigmoidf(pf0) * c0r + sigmoidf(pi0) * fast_tanh(pg0);
                c1r = sigmoidf(pf1) * c1r + sigmoidf(pi1) * fast_tanh(pg1);
                float hv0 = sigmoidf(po0) * fast_tanh(c0r);
                float hv1 = sigmoidf(po1) * fast_tanh(c1r);
                h0l = hv0; h1l = hv1;
                bf16u h0h = f2bf(hv0); bf16u h0lo = f2bf(hv0 - bf2f(h0h));
                bf16u h1h = f2bf(hv1); bf16u h1lo = f2bf(hv1 - bf2f(h1h));
                uint32 hiw = (uint32)h0h | ((uint32)h1h << 16);
                uint32 low = (uint32)h0lo | ((uint32)h1lo << 16);
                __hip_atomic_store(&hW[wbase], hiw,
                                   __ATOMIC_RELAXED, __HIP_MEMORY_SCOPE_AGENT);
                __hip_atomic_store(&hW[PL + wbase], low,
                                   __ATOMIC_RELAXED, __HIP_MEMORY_SCOPE_AGENT);
                if (l == 3)
                    y3bm[(size_t)t * 6144 + wbase] = hiw;   // dense full lines
            }
        }
        scoped_barrier(flags, (uint32)(r + 2), tid, l, bid);
    }

    if (tid < 128) {
        hs_out[(size_t)l * 12288 + ub * 384 + jg0]     = h0l;
        hs_out[(size_t)l * 12288 + ub * 384 + jg0 + 1] = h1l;
        cs_out[(size_t)l * 12288 + ub * 384 + jg0]     = c0r;
        cs_out[(size_t)l * 12288 + ub * 384 + jg0 + 1] = c1r;
    }
}

// ---------------------------------------------------------------------------
// y3 block-major [t][48][32][4u32] -> standard [t*32+b][384] bf16.
// One block per t; LDS transpose, coalesced both sides.
// ---------------------------------------------------------------------------
__global__ void __launch_bounds__(256) transpose_y_kernel(
    const uint32* __restrict__ in, uint32* __restrict__ out)
{
    const int t = blockIdx.x;
    const int tid = threadIdx.x;
    __shared__ uint32 lds[32 * 197];
    const uint32* src = in + (size_t)t * 6144;
    #pragma unroll
    for (int k = 0; k < 24; ++k) {
        int i = k * 256 + tid;
        int sub = i >> 7, b = (i >> 2) & 31, q = i & 3;
        lds[b * 197 + sub * 4 + q] = src[i];
    }
    __syncthreads();
    uint32* dst = out + (size_t)t * 32 * 192;
    #pragma unroll
    for (int k = 0; k < 24; ++k) {
        int i = k * 256 + tid;
        int b = i / 192, c = i - b * 192;
        dst[b * 192 + c] = lds[b * 197 + c];
    }
}

// ---------------------------------------------------------------------------
// Causal flash attention, MFMA version (round-9). Per block: 32 q-rows of
// one batch; k-tiles of 32 keys. QK^T: 32x32x16 MFMAs, d-dim (K=384) split
// across 4 waves -> 4 partial slabs (lstm-verified frag layouts: A lane =
// row l&31 with k-span (l>>5)*8; D col=lane&31, row=(reg&3)+8*(reg>>2)+
// 4*(lane>>5)). Softmax (32 threads) sums slabs, online max/sum, writes
// P as hi/lo bf16 (fp32 fidelity). PV: A=P, B=V^T (transposed at staging),
// 12 MFMAs/wave/tile accumulating O in registers with alpha-rescale.
// Dynamic LDS 118656 B. All layouts 16-B aligned for ds_read_b128.
// ---------------------------------------------------------------------------
__global__ void __launch_bounds__(256, 1) attn_kernel(
    const bf16u* __restrict__ outy, const bf16u* __restrict__ keys,
    bf16u* __restrict__ ctxv)
{
    extern __shared__ char smem[];
    uint32* Qs  = (uint32*)smem;                    // [32][204] u32 (bf16 stride 408)
    uint32* Ks  = (uint32*)(smem + 26112);          // [32][204] u32
    bf16u*  Vt  = (bf16u*)(smem + 52224);           // [384][56] bf16 (V transposed)
    float*  Ss  = (float*)(smem + 95232);           // [4][32][33] f32 slabs
    bf16u*  Ph  = (bf16u*)(smem + 112128);          // [32][48] bf16
    bf16u*  Pl  = (bf16u*)(smem + 115200);          // [32][48] bf16
    float*  m_s = (float*)(smem + 118272);          // 32
    float*  l_s = m_s + 32;
    float*  al_s = m_s + 64;                        // end: 118656

    const int b = blockIdx.y;
    const int q0 = blockIdx.x * 32;
    const int tid = threadIdx.x;
    const int wave = tid >> 6, lane = tid & 63;
    const int lrow = lane & 31, lhalf = lane >> 5;

    for (int i = tid; i < 32 * 192; i += 256) {
        int q = i / 192, dp = i - q * 192;
        Qs[q * 204 + dp] = ((const uint32*)outy)[((size_t)(q0 + q) * 32 + b) * 192 + dp];
    }
    if (tid < 32) { m_s[tid] = -3e38f; l_s[tid] = 0.f; }

    f16v O[3];
    #pragma unroll
    for (int g = 0; g < 3; ++g)
        #pragma unroll
        for (int r = 0; r < 16; ++r) O[g][r] = 0.f;

    const int nkt = blockIdx.x + 1;
    for (int kt = 0; kt < nkt; ++kt) {
        const int k0 = kt * 32;
        __syncthreads();   // prev tile's QK (Ks) + PV (Vt) done before restage
        for (int i = tid; i < 32 * 192; i += 256) {
            int kk = i / 192, dp = i - kk * 192;
            size_t rb = ((size_t)(k0 + kk) * 32 + b) * 192;
            Ks[kk * 204 + dp] = ((const uint32*)keys)[rb + dp];
            uint32 vv = ((const uint32*)outy)[rb + dp];
            Vt[(2 * dp) * 56 + kk]     = (bf16u)(vv & 0xffffu);
            Vt[(2 * dp + 1) * 56 + kk] = (bf16u)(vv >> 16);
        }
        __syncthreads();

        // ---- QK^T partials: wave w owns d-chunks [w*6, w*6+6) of 24 ----
        {
            f16v s;
            #pragma unroll
            for (int r = 0; r < 16; ++r) s[r] = 0.f;
            #pragma unroll
            for (int i6 = 0; i6 < 6; ++i6) {
                const int kc = wave * 6 + i6;
                s8v a  = *(const s8v*)((const bf16u*)Qs + lrow * 408 + kc * 16 + lhalf * 8);
                s8v kb = *(const s8v*)((const bf16u*)Ks + lrow * 408 + kc * 16 + lhalf * 8);
                s = __builtin_amdgcn_mfma_f32_32x32x16_bf16(a, kb, s, 0, 0, 0);
            }
            float* ps = Ss + wave * 1056;
            #pragma unroll
            for (int r = 0; r < 16; ++r) {
                const int q = (r & 3) + 8 * (r >> 2) + 4 * lhalf;
                ps[q * 33 + lrow] = s[r];
            }
        }
        __syncthreads();

        // ---- softmax: thread q sums 4 slabs, online max/sum, P -> hi/lo ----
        if (tid < 32) {
            const int q = tid;
            float sv[32];
            float mt = m_s[q];
            #pragma unroll
            for (int k = 0; k < 32; ++k) {
                float s = Ss[q * 33 + k] + Ss[1056 + q * 33 + k]
                        + Ss[2112 + q * 33 + k] + Ss[3168 + q * 33 + k];
                s *= 0.051031036307982884f;   // 1/sqrt(384)
                sv[k] = ((k0 + k) <= (q0 + q)) ? s : -1e30f;
                mt = fmaxf(mt, sv[k]);
            }
            float alpha = __expf(m_s[q] - mt);
            float l = l_s[q] * alpha;
            #pragma unroll
            for (int k = 0; k < 32; ++k) {
                float pv = __expf(sv[k] - mt);
                l += pv;
                bf16u ph = f2bf(pv);
                Ph[q * 48 + k] = ph;
                Pl[q * 48 + k] = f2bf(pv - bf2f(ph));
            }
            m_s[q] = mt; l_s[q] = l; al_s[q] = alpha;
        }
        __syncthreads();

        // ---- rescale O by alpha, then PV: wave w owns d-groups w*3..w*3+2 ----
        {
            float ar[16];
            #pragma unroll
            for (int r = 0; r < 16; ++r)
                ar[r] = al_s[(r & 3) + 8 * (r >> 2) + 4 * lhalf];
            #pragma unroll
            for (int g = 0; g < 3; ++g)
                #pragma unroll
                for (int r = 0; r < 16; ++r) O[g][r] *= ar[r];

            s8v pa0 = *(const s8v*)(Ph + lrow * 48 + lhalf * 8);
            s8v pa1 = *(const s8v*)(Ph + lrow * 48 + 16 + lhalf * 8);
            s8v pl0 = *(const s8v*)(Pl + lrow * 48 + lhalf * 8);
            s8v pl1 = *(const s8v*)(Pl + lrow * 48 + 16 + lhalf * 8);
            #pragma unroll
            for (int g = 0; g < 3; ++g) {
                const int d = (wave * 3 + g) * 32 + lrow;
                s8v v0 = *(const s8v*)(Vt + d * 56 + lhalf * 8);
                s8v v1 = *(const s8v*)(Vt + d * 56 + 16 + lhalf * 8);
                O[g] = __builtin_amdgcn_mfma_f32_32x32x16_bf16(pa0, v0, O[g], 0, 0, 0);
                O[g] = __builtin_amdgcn_mfma_f32_32x32x16_bf16(pl0, v0, O[g], 0, 0, 0);
                O[g] = __builtin_amdgcn_mfma_f32_32x32x16_bf16(pa1, v1, O[g], 0, 0, 0);
                O[g] = __builtin_amdgcn_mfma_f32_32x32x16_bf16(pl1, v1, O[g], 0, 0, 0);
            }
        }
    }

    // ---- finalize: O * (1/l), stage bf16 in Ks region, coalesced store ----
    __syncthreads();
    if (tid < 32) al_s[tid] = 1.f / l_s[tid];
    __syncthreads();
    {
        float ir[16];
        #pragma unroll
        for (int r = 0; r < 16; ++r)
            ir[r] = al_s[(r & 3) + 8 * (r >> 2) + 4 * lhalf];
        bf16u* Os = (bf16u*)Ks;   // reuse: [32][408] bf16
        #pragma unroll
        for (int g = 0; g < 3; ++g) {
            const int d = (wave * 3 + g) * 32 + lrow;
            #pragma unroll
            for (int r = 0; r < 16; ++r) {
                const int q = (r & 3) + 8 * (r >> 2) + 4 * lhalf;
                Os[q * 408 + d] = f2bf(O[g][r] * ir[r]);
            }
        }
    }
    __syncthreads();
    for (int i = tid; i < 32 * 192; i += 256) {
        int q = i / 192, dp = i - q * 192;
        ((uint32*)ctxv)[((size_t)(q0 + q) * 32 + b) * 192 + dp] = Ks[q * 204 + dp];
    }
}

// ---------------------------------------------------------------------------
extern "C" void kernel_launch(void* const* d_in, const int* in_sizes, int n_in,
                              void* d_out, int out_size, void* d_ws, size_t ws_size,
                              hipStream_t stream) {
    (void)in_sizes; (void)n_in; (void)out_size; (void)ws_size;
    const int*   x        = (const int*)d_in[0];
    const float* context  = (const float*)d_in[1];
    const float* h_in     = (const float*)d_in[2];
    const float* c_in     = (const float*)d_in[3];
    const float* emb      = (const float*)d_in[4];
    const float* ctx_W    = (const float*)d_in[5];
    const float* ctx_b    = (const float*)d_in[6];
    const float* Wih0     = (const float*)d_in[7];
    const float* Wih_rest = (const float*)d_in[8];
    const float* Whh      = (const float*)d_in[9];
    const float* bih      = (const float*)d_in[10];
    const float* bhh      = (const float*)d_in[11];
    const float* Wa       = (const float*)d_in[12];
    const float* comb_W   = (const float*)d_in[13];
    const float* comb_b   = (const float*)d_in[14];
    const float* fc_W     = (const float*)d_in[15];
    const float* fc_b     = (const float*)d_in[16];
    float* out = (float*)d_out;

    // ---- workspace layout, ~76 MB peak ----
    char* wsb = (char*)d_ws;
    uint32* flags = (uint32*)(wsb + 0);               //  32 KB (192 lines)
    uint32* hbuf  = (uint32*)(wsb + 32768);           // 393 KB dense block-major
    uint32* y3bm  = (uint32*)(wsb + 458752);          // 25.17 MB [1024][6144]u32
    bf16u*  y3    = (bf16u*)(wsb + 25624576ull);      // 25.17 MB standard layout
    bf16u*  inp   = (bf16u*)(wsb + 50790400ull);      // 16.78 MB (region 25.17)
    bf16u*  keysu = (bf16u*)(wsb + 50790400ull);      // reuse (inp dead post-lstm)
    bf16u*  ctxvu = (bf16u*)(wsb + 458752);           // reuse (y3bm dead post-transpose)
    bf16u*  combu = (bf16u*)(wsb + 50790400ull);      // reuse (keys dead post-attn)

    hipMemsetAsync(d_ws, 0, 32768, stream);           // zero flags

    static int smem_set = 0;
    if (!smem_set) {
        hipFuncSetAttribute((const void*)lstm_wave_kernel,
                            hipFuncAttributeMaxDynamicSharedMemorySize, 67072);
        hipFuncSetAttribute((const void*)attn_kernel,
                            hipFuncAttributeMaxDynamicSharedMemorySize, 118656);
        smem_set = 1;
    }

    embed_ctx_kernel<<<2048, 128, 0, stream>>>(x, context, emb, ctx_W, ctx_b, inp);

    const size_t HS_OFF = (size_t)32768 * 100;
    // dynamic LDS: Wih planes (max 50176 B at l>0) + 4 gate slabs 16896 B
    lstm_wave_kernel<<<192, 256, 67072, stream>>>(
        inp, Wih0, Wih_rest, Whh, bih, bhh, h_in, c_in,
        y3bm, hbuf, flags, out + HS_OFF, out + HS_OFF + 49152);

    transpose_y_kernel<<<1024, 256, 0, stream>>>(y3bm, (uint32*)y3);

    // keys = y3 @ Wa^T
    gemm_kernel<<<dim3(6, 512), 256, 0, stream>>>(
        y3, nullptr, 384, Wa, nullptr, keysu, 32768, 384, 384, 1);
    // ctx_vec (flash attention, MFMA)
    attn_kernel<<<dim3(32, 32), 256, 118656, stream>>>(y3, keysu, ctxvu);
    // combined = tanh([y3, ctx] @ comb_W^T + b)
    gemm_kernel<<<dim3(6, 512), 256, 0, stream>>>(
        y3, ctxvu, 384, comb_W, comb_b, combu, 32768, 384, 768, 2);
    // logits = combined @ fc_W^T + fc_b  -> d_out permuted [b][t][100]
    gemm_kernel<<<dim3(2, 512), 256, 0, stream>>>(
        combu, nullptr, 384, fc_W, fc_b, out, 32768, 100, 384, 3);
}

// Round 10
// 6323.972 us; speedup vs baseline: 1.1760x; 1.0034x over previous
//
#include <hip/hip_runtime.h>

typedef unsigned int  uint32;
typedef unsigned long long u64;
typedef unsigned short bf16u;
typedef __attribute__((ext_vector_type(8))) short s8v;     // 8 bf16 (4 VGPRs)
typedef __attribute__((ext_vector_type(4))) float f4v;     // 16x16 MFMA acc
typedef __attribute__((ext_vector_type(16))) float f16v;   // 32x32 MFMA acc

#define PL   6144            // u32 per plane  (48 sub * 32 b * 4 u32)
#define PL64 3072            // u64 per plane
#define PAR  12288           // u32 per parity (2 planes)
#define HB2  24576           // u32 per layer  (2 parities)

__device__ __forceinline__ float fast_tanh(float x) {
    x = fminf(9.f, fmaxf(-9.f, x));
    float e = __expf(2.f * x);
    return (e - 1.f) / (e + 1.f);
}
__device__ __forceinline__ float sigmoidf(float x) {
    return 1.f / (1.f + __expf(-x));
}
__device__ __forceinline__ bf16u f2bf(float f) {
    uint32 u = __float_as_uint(f);
    u += 0x7fffu + ((u >> 16) & 1u);
    return (bf16u)(u >> 16);
}
__device__ __forceinline__ float bf2f(bf16u u) {
    return __uint_as_float(((uint32)u) << 16);
}
__device__ __forceinline__ uint32 pack2bf(float lo, float hi) {
    return (uint32)f2bf(lo) | ((uint32)f2bf(hi) << 16);
}
__device__ __forceinline__ float bflo(uint32 p) { return __uint_as_float(p << 16); }
__device__ __forceinline__ float bfhi(uint32 p) { return __uint_as_float(p & 0xffff0000u); }

// 16-B A-fragment load straight from the dense broadcast buffer to VGPRs.
// Agent-scope relaxed atomics -> bypass stale L1/L2, hit LLC.
__device__ __forceinline__ s8v ldfrag(const u64* p) {
    union { u64 q[2]; s8v v; } u;
    u.q[0] = __hip_atomic_load(p,     __ATOMIC_RELAXED, __HIP_MEMORY_SCOPE_AGENT);
    u.q[1] = __hip_atomic_load(p + 1, __ATOMIC_RELAXED, __HIP_MEMORY_SCOPE_AGENT);
    return u.v;
}

// ---------------------------------------------------------------------------
// Embedding + context projection -> inp [rt=t*32+b][256] bf16 (emb || ctx)
// ---------------------------------------------------------------------------
__global__ void __launch_bounds__(128) embed_ctx_kernel(
    const int* __restrict__ x, const float* __restrict__ ctx,
    const float* __restrict__ emb, const float* __restrict__ ctxW,
    const float* __restrict__ ctxb, bf16u* __restrict__ inp)
{
    const int r0 = blockIdx.x * 16;
    const int tid = threadIdx.x;
    __shared__ float cs[16][301];
    __shared__ int xs[16];
    for (int i = tid; i < 16 * 300; i += 128) {
        int row = i / 300, k = i - row * 300;
        int rt = r0 + row, b = rt & 31, t = rt >> 5;
        cs[row][k] = ctx[((size_t)b * 1024 + t) * 300 + k];
    }
    if (tid < 16) {
        int rt = r0 + tid;
        xs[tid] = x[(rt & 31) * 1024 + (rt >> 5)];
    }
    __syncthreads();
    float acc[16];
    #pragma unroll
    for (int row = 0; row < 16; ++row) acc[row] = 0.f;
    for (int k = 0; k < 300; ++k) {
        float w = ctxW[tid * 300 + k];
        #pragma unroll
        for (int row = 0; row < 16; ++row) acc[row] = fmaf(w, cs[row][k], acc[row]);
    }
    float bb = ctxb[tid];
    for (int row = 0; row < 16; ++row) {
        size_t base = (size_t)(r0 + row) * 256;
        inp[base + tid]       = f2bf(emb[xs[row] * 128 + tid]);
        inp[base + 128 + tid] = f2bf(acc[row] + bb);
    }
}

// ---------------------------------------------------------------------------
// MFMA GEMM (round-10: BM=128): C[M,N] = A[M,K](bf16) @ W[N,K]^T(f32 hi/lo).
// 256 threads = 4 waves; wave w owns rows [w*32, w*32+32) of the 128-row
// tile (2 mtiles x 4 ntiles x hi/lo = 16 MFMAs per K-step per wave — 2x the
// MFMA work per barrier pair of the old 64x64 tile, and half the bm-blocks
// re-converting W). A split at K0 between A0/A1. mode 1: bf16 out;
// 2: bf16+tanh; 3: f32 out, row rt->(b*1024+t) (logits). BN=64, BK=32.
// ---------------------------------------------------------------------------
__global__ void __launch_bounds__(256) gemm_kernel(
    const bf16u* __restrict__ A0, const bf16u* __restrict__ A1, int K0,
    const float* __restrict__ W, const float* __restrict__ bias1,
    void* __restrict__ Cout, int M, int N, int K, int mode)
{
    __shared__ bf16u As[128][40];
    __shared__ bf16u Whi[64][40];
    __shared__ bf16u Wlo[64][40];
    const int tid = threadIdx.x;
    const int bn = blockIdx.x * 64, bm = blockIdx.y * 128;
    const int wave = tid >> 6, lane = tid & 63;
    const int ncol = lane & 15, quad = lane >> 4;
    const int lr = tid >> 2, lk = (tid & 3) * 8;

    f4v acc[2][4];
    #pragma unroll
    for (int i = 0; i < 2; ++i)
        #pragma unroll
        for (int j = 0; j < 4; ++j) acc[i][j] = (f4v){0.f, 0.f, 0.f, 0.f};

    const int wrow = bn + lr;
    for (int k0 = 0; k0 < K; k0 += 32) {
        const bf16u* Ab; int kb, lda;
        if (k0 < K0) { Ab = A0; kb = k0; lda = K0; }
        else         { Ab = A1; kb = k0 - K0; lda = K - K0; }
        uint4 av0 = *(const uint4*)(Ab + (size_t)(bm + lr) * lda + kb + lk);
        uint4 av1 = *(const uint4*)(Ab + (size_t)(bm + 64 + lr) * lda + kb + lk);
        float4 w0 = make_float4(0.f, 0.f, 0.f, 0.f), w1 = w0;
        if (wrow < N) {
            const float* wp = W + (size_t)wrow * K + k0 + lk;
            w0 = *(const float4*)wp;
            w1 = *(const float4*)(wp + 4);
        }
        __syncthreads();
        *(uint4*)&As[lr][lk] = av0;
        *(uint4*)&As[64 + lr][lk] = av1;
        {
            bf16u h[8], l[8];
            float wf[8] = {w0.x, w0.y, w0.z, w0.w, w1.x, w1.y, w1.z, w1.w};
            #pragma unroll
            for (int j = 0; j < 8; ++j) {
                h[j] = f2bf(wf[j]);
                l[j] = f2bf(wf[j] - bf2f(h[j]));
            }
            #pragma unroll
            for (int j = 0; j < 8; ++j) Whi[lr][lk + j] = h[j];
            #pragma unroll
            for (int j = 0; j < 8; ++j) Wlo[lr][lk + j] = l[j];
        }
        __syncthreads();
        s8v aF[2], bH[4], bL[4];
        #pragma unroll
        for (int mt = 0; mt < 2; ++mt)
            aF[mt] = *(const s8v*)&As[wave * 32 + mt * 16 + ncol][quad * 8];
        #pragma unroll
        for (int nt = 0; nt < 4; ++nt) {
            bH[nt] = *(const s8v*)&Whi[nt * 16 + ncol][quad * 8];
            bL[nt] = *(const s8v*)&Wlo[nt * 16 + ncol][quad * 8];
        }
        #pragma unroll
        for (int mt = 0; mt < 2; ++mt)
            #pragma unroll
            for (int nt = 0; nt < 4; ++nt) {
                acc[mt][nt] = __builtin_amdgcn_mfma_f32_16x16x32_bf16(
                    aF[mt], bH[nt], acc[mt][nt], 0, 0, 0);
                acc[mt][nt] = __builtin_amdgcn_mfma_f32_16x16x32_bf16(
                    aF[mt], bL[nt], acc[mt][nt], 0, 0, 0);
            }
    }

    #pragma unroll
    for (int nt = 0; nt < 4; ++nt) {
        const int col = bn + nt * 16 + ncol;
        if (col >= N) continue;
        float bb = bias1 ? bias1[col] : 0.f;
        #pragma unroll
        for (int mt = 0; mt < 2; ++mt) {
            const int rowb = bm + wave * 32 + mt * 16 + quad * 4;
            if (mode == 3) {
                #pragma unroll
                for (int r = 0; r < 4; ++r) {
                    int row = rowb + r;
                    int b = row & 31, t = row >> 5;
                    ((float*)Cout)[((size_t)b * 1024 + t) * (size_t)N + col] =
                        acc[mt][nt][r] + bb;
                }
            } else {
                #pragma unroll
                for (int r = 0; r < 4; ++r) {
                    float v = acc[mt][nt][r] + bb;
                    if (mode == 2) v = fast_tanh(v);
                    ((bf16u*)Cout)[(size_t)(rowb + r) * N + col] = f2bf(v);
                }
            }
        }
    }
}

// ---------------------------------------------------------------------------
// Scoped flag barrier (round-6 verified): per-block flag on its OWN 128-B
// line (packing sync lines funnels traffic through few LLC slices: +2us/rd).
// Poll only the 3-layer stencil {l-1, l, l+1}.
// ---------------------------------------------------------------------------
__device__ __forceinline__ void scoped_barrier(uint32* flags, uint32 r,
                                               int tid, int l, int bid) {
    __syncthreads();
    if (tid == 0)
        __hip_atomic_store(&flags[bid * 32], r, __ATOMIC_RELAXED, __HIP_MEMORY_SCOPE_AGENT);
    const int lo = (l > 0) ? (l - 1) * 48 : 0;
    const int nf = ((l > 0) + 1 + (l < 3)) * 48;
    if (tid < nf) {
        while (__hip_atomic_load(&flags[(lo + tid) * 32], __ATOMIC_RELAXED,
                                 __HIP_MEMORY_SCOPE_AGENT) < r)
            __builtin_amdgcn_s_sleep(1);
    }
    __syncthreads();
}

// ---------------------------------------------------------------------------
// Layer-wavefront LSTM (round-6 verified): 4 layers x 1024 steps, ONE launch,
// 1027 rounds. 192 blocks = 4 layers x 48 sub-blocks x 8 hidden dims.
// Gate MFMAs are 32x32x16, K-split across the 4 waves (each A-fragment
// loaded exactly once per block). Partial tiles -> 4 LDS slabs summed by
// update threads. h broadcast: BLOCK-MAJOR DENSE
// [layer][parity][plane][sub][b][4u32]; A-frag (kt16,khalf,row) = 16 B at
// u64 index ((kt16*2+khalf)*32+row)*2.
// ---------------------------------------------------------------------------
__global__ void __launch_bounds__(256, 1) lstm_wave_kernel(
    const bf16u* __restrict__ inp,   // [t*32+b][256] bf16
    const float* __restrict__ Wih0,  // [1536][256]
    const float* __restrict__ WihR,  // [3][1536][384]
    const float* __restrict__ Whh,   // [4][1536][384]
    const float* __restrict__ bih, const float* __restrict__ bhh,
    const float* __restrict__ h_in, const float* __restrict__ c_in,
    uint32* __restrict__ y3bm,       // [1024][48][32][4] u32 (hi plane only)
    uint32* __restrict__ hbuf,       // [4][2][2][48][32][4] u32
    uint32* __restrict__ flags,      // 192 flags, 128-B spaced
    float* __restrict__ hs_out, float* __restrict__ cs_out)
{
    extern __shared__ char sm[];
    const int tid = threadIdx.x, bid = blockIdx.x;
    const int l = bid / 48, sub = bid - l * 48;
    const int j0 = sub * 8;
    const int wave = tid >> 6, lane = tid & 63;
    const int row32 = lane & 31;              // A row (batch) / B row (gate)
    const int khalf = lane >> 5;              // k-half within a 16-chunk
    const int n = row32;                      // local gate-row for B/D col

    const int Kx = l ? 384 : 256;
    const int WSTR = l ? 392 : 264;           // padded bf16 stride
    const int wbytes = 2 * 32 * WSTR * 2;     // Wih planes bytes
    bf16u* wlds  = (bf16u*)sm;
    float* gates = (float*)(sm + wbytes);     // 4 slabs x 1056 f32 = 16896 B

    const float* WhhL = Whh + (size_t)l * 1536 * 384;
    const float* WihL = l ? (WihR + (size_t)(l - 1) * 1536 * 384) : Wih0;
    const float* bihL = bih + l * 1536;
    const float* bhhL = bhh + l * 1536;
    uint32* hbL = hbuf + (size_t)l * HB2;
    uint32* ybL = l ? (hbuf + (size_t)(l - 1) * HB2) : nullptr;

    const int h0c = wave * 6;                 // this wave's h/y k16-chunks
    const int x0c = wave * 4;                 // l0 x k16-chunks

    // ---- Whh B-frags in registers (hi/lo): rows = ALL 32 local gates,
    //      k = this wave's 6 chunks x khalf ----
    s8v Bh6[6], Bl6[6];
    {
        const int wrow = (n >> 3) * 384 + j0 + (n & 7);
        #pragma unroll
        for (int i = 0; i < 6; ++i) {
            const float* wp = WhhL + (size_t)wrow * 384 + (h0c + i) * 16 + khalf * 8;
            s8v hi, lo;
            #pragma unroll
            for (int j = 0; j < 8; ++j) {
                float w = wp[j];
                bf16u wh = f2bf(w);
                bf16u wl = f2bf(w - bf2f(wh));
                hi[j] = (short)wh; lo[j] = (short)wl;
            }
            Bh6[i] = hi; Bl6[i] = lo;
        }
    }
    // ---- Wih slice into LDS (hi/lo planes) ----
    for (int r2 = 0; r2 < 32; ++r2) {
        int rg = (r2 >> 3) * 384 + j0 + (r2 & 7);
        for (int k = tid; k < Kx; k += 256) {
            float w = WihL[(size_t)rg * Kx + k];
            bf16u wh = f2bf(w);
            wlds[r2 * WSTR + k] = wh;
            wlds[32 * WSTR + r2 * WSTR + k] = f2bf(w - bf2f(wh));
        }
    }

    // update role: tid<128 owns (batch ub, dim pair jg0, jg0+1)
    const int ub = tid & 31, jp = tid >> 5;          // jp 0..3 for tid<128
    const int jg0 = j0 + 2 * jp;
    const int wbase = (sub * 32 + ub) * 4 + jp;      // dense u32 index
    float c0r = 0.f, c1r = 0.f, h0l = 0.f, h1l = 0.f;
    float bI0 = 0, bF0 = 0, bG0 = 0, bO0 = 0, bI1 = 0, bF1 = 0, bG1 = 0, bO1 = 0;

    if (tid < 128) {
        bI0 = bihL[jg0] + bhhL[jg0];
        bF0 = bihL[384 + jg0] + bhhL[384 + jg0];
        bG0 = bihL[768 + jg0] + bhhL[768 + jg0];
        bO0 = bihL[1152 + jg0] + bhhL[1152 + jg0];
        bI1 = bihL[jg0 + 1] + bhhL[jg0 + 1];
        bF1 = bihL[384 + jg0 + 1] + bhhL[384 + jg0 + 1];
        bG1 = bihL[768 + jg0 + 1] + bhhL[768 + jg0 + 1];
        bO1 = bihL[1152 + jg0 + 1] + bhhL[1152 + jg0 + 1];
        float ha = h_in[(size_t)l * 12288 + ub * 384 + jg0];
        float hb = h_in[(size_t)l * 12288 + ub * 384 + jg0 + 1];
        bf16u ha_h = f2bf(ha); bf16u ha_l = f2bf(ha - bf2f(ha_h));
        bf16u hb_h = f2bf(hb); bf16u hb_l = f2bf(hb - bf2f(hb_h));
        __hip_atomic_store(&hbL[wbase],
                           (uint32)ha_h | ((uint32)hb_h << 16),
                           __ATOMIC_RELAXED, __HIP_MEMORY_SCOPE_AGENT);
        __hip_atomic_store(&hbL[PL + wbase],
                           (uint32)ha_l | ((uint32)hb_l << 16),
                           __ATOMIC_RELAXED, __HIP_MEMORY_SCOPE_AGENT);
        c0r = c_in[(size_t)l * 12288 + ub * 384 + jg0];
        c1r = c_in[(size_t)l * 12288 + ub * 384 + jg0 + 1];
    }
    scoped_barrier(flags, 1u, tid, l, bid);

    for (int r = 0; r < 1027; ++r) {
        const int t = r - l;
        if ((unsigned)t < 1024u) {
            const u64* hB = (const u64*)(hbL + (t & 1) * PAR);
            uint32* hW = hbL + ((t + 1) & 1) * PAR;

            f16v cHH = {0.f,0.f,0.f,0.f,0.f,0.f,0.f,0.f,
                        0.f,0.f,0.f,0.f,0.f,0.f,0.f,0.f};
            f16v cLH = cHH, cHL = cHH;

            // ---- h @ Whh^T : this wave's 6 k16-chunks, frags loaded once ----
            #pragma unroll
            for (int i = 0; i < 6; ++i) {
                const int kt = h0c + i;
                const int co = ((kt * 2 + khalf) * 32 + row32) * 2;
                s8v Ah = ldfrag(hB + co);
                s8v Al = ldfrag(hB + PL64 + co);
                cHH = __builtin_amdgcn_mfma_f32_32x32x16_bf16(Ah, Bh6[i], cHH, 0, 0, 0);
                cLH = __builtin_amdgcn_mfma_f32_32x32x16_bf16(Al, Bh6[i], cLH, 0, 0, 0);
                cHL = __builtin_amdgcn_mfma_f32_32x32x16_bf16(Ah, Bl6[i], cHL, 0, 0, 0);
            }
            if (l) {
                const u64* yB = (const u64*)(ybL + ((t + 1) & 1) * PAR);
                #pragma unroll
                for (int i = 0; i < 6; ++i) {
                    const int kt = h0c + i;
                    const int co = ((kt * 2 + khalf) * 32 + row32) * 2;
                    s8v Ayh = ldfrag(yB + co);
                    s8v Ayl = ldfrag(yB + PL64 + co);
                    s8v Bxh = *(const s8v*)&wlds[n * 392 + kt * 16 + khalf * 8];
                    s8v Bxl = *(const s8v*)&wlds[32 * 392 + n * 392 + kt * 16 + khalf * 8];
                    cHH = __builtin_amdgcn_mfma_f32_32x32x16_bf16(Ayh, Bxh, cHH, 0, 0, 0);
                    cLH = __builtin_amdgcn_mfma_f32_32x32x16_bf16(Ayl, Bxh, cLH, 0, 0, 0);
                    cHL = __builtin_amdgcn_mfma_f32_32x32x16_bf16(Ayh, Bxl, cHL, 0, 0, 0);
                }
            } else {
                const uint4* irow = (const uint4*)(inp + ((size_t)t * 32 + row32) * 256);
                #pragma unroll
                for (int i = 0; i < 4; ++i) {
                    const int kt = x0c + i;
                    union { uint4 u; s8v v; } cv;
                    cv.u = irow[kt * 2 + khalf];
                    s8v Bxh = *(const s8v*)&wlds[n * 264 + kt * 16 + khalf * 8];
                    s8v Bxl = *(const s8v*)&wlds[32 * 264 + n * 264 + kt * 16 + khalf * 8];
                    cHH = __builtin_amdgcn_mfma_f32_32x32x16_bf16(cv.v, Bxh, cHH, 0, 0, 0);
                    cHL = __builtin_amdgcn_mfma_f32_32x32x16_bf16(cv.v, Bxl, cHL, 0, 0, 0);
                }
            }
            // ---- partial tile -> this wave's LDS slab ----
            {
                float* ps = gates + wave * 1056;
                #pragma unroll
                for (int reg = 0; reg < 16; ++reg) {
                    const int brow = (reg & 3) + 8 * (reg >> 2) + 4 * khalf;
                    ps[n * 33 + brow] = cHH[reg] + cLH[reg] + cHL[reg];
                }
            }
            __syncthreads();

            // ---- cell update: tid<128, 2 dims each; sum 4 K-partials ----
            if (tid < 128) {
                const int jj0 = 2 * jp, jj1 = 2 * jp + 1;
                #define GS(g) (gates[(g) * 33 + ub] + gates[1056 + (g) * 33 + ub] + \
                               gates[2112 + (g) * 33 + ub] + gates[3168 + (g) * 33 + ub])
                float pi0 = GS(jj0)      + bI0;
                float pf0 = GS(8 + jj0)  + bF0;
                float pg0 = GS(16 + jj0) + bG0;
                float po0 = GS(24 + jj0) + bO0;
                float pi1 = GS(jj1)      + bI1;
                float pf1 = GS(8 + jj1)  + bF1;
                float pg1 = GS(16 + jj1) + bG1;
                float po1 = GS(24 + jj1) + bO1;
                #undef GS
                c0r = sigmoidf(pf0) * c0r + sigmoidf(pi0) * fast_tanh(pg0);
                c1r = sigmoidf(pf1) * c1r + sigmoidf(pi1) * fast_tanh(pg1);
                float hv0 = sigmoidf(po0) * fast_tanh(c0r);
                float hv1 = sigmoidf(po1) * fast_tanh(c1r);
                h0l = hv0; h1l = hv1;
                bf16u h0h = f2bf(hv0); bf16u h0lo = f2bf(hv0 - bf2f(h0h));
                bf16u h1h = f2bf(hv1); bf16u h1lo = f2bf(hv1 - bf2f(h1h));
                uint32 hiw = (uint32)h0h | ((uint32)h1h << 16);
                uint32 low = (uint32)h0lo | ((uint32)h1lo << 16);
                __hip_atomic_store(&hW[wbase], hiw,
                                   __ATOMIC_RELAXED, __HIP_MEMORY_SCOPE_AGENT);
                __hip_atomic_store(&hW[PL + wbase], low,
                                   __ATOMIC_RELAXED, __HIP_MEMORY_SCOPE_AGENT);
                if (l == 3)
                    y3bm[(size_t)t * 6144 + wbase] = hiw;   // dense full lines
            }
        }
        scoped_barrier(flags, (uint32)(r + 2), tid, l, bid);
    }

    if (tid < 128) {
        hs_out[(size_t)l * 12288 + ub * 384 + jg0]     = h0l;
        hs_out[(size_t)l * 12288 + ub * 384 + jg0 + 1] = h1l;
        cs_out[(size_t)l * 12288 + ub * 384 + jg0]     = c0r;
        cs_out[(size_t)l * 12288 + ub * 384 + jg0 + 1] = c1r;
    }
}

// ---------------------------------------------------------------------------
// y3 block-major [t][48][32][4u32] -> standard [t*32+b][384] bf16.
// One block per t; LDS transpose, coalesced both sides.
// ---------------------------------------------------------------------------
__global__ void __launch_bounds__(256) transpose_y_kernel(
    const uint32* __restrict__ in, uint32* __restrict__ out)
{
    const int t = blockIdx.x;
    const int tid = threadIdx.x;
    __shared__ uint32 lds[32 * 197];
    const uint32* src = in + (size_t)t * 6144;
    #pragma unroll
    for (int k = 0; k < 24; ++k) {
        int i = k * 256 + tid;
        int sub = i >> 7, b = (i >> 2) & 31, q = i & 3;
        lds[b * 197 + sub * 4 + q] = src[i];
    }
    __syncthreads();
    uint32* dst = out + (size_t)t * 32 * 192;
    #pragma unroll
    for (int k = 0; k < 24; ++k) {
        int i = k * 256 + tid;
        int b = i / 192, c = i - b * 192;
        dst[b * 192 + c] = lds[b * 197 + c];
    }
}

// ---------------------------------------------------------------------------
// Causal flash attention, MFMA version (round-9 verified). Per block: 32
// q-rows of one batch; k-tiles of 32 keys. QK^T: 32x32x16 MFMAs, d-dim
// split across 4 waves -> 4 partial slabs. Softmax (32 threads) sums slabs,
// online max/sum, P as hi/lo bf16. PV: A=P, B=V^T (transposed at staging),
// O in registers with alpha-rescale. Dynamic LDS 118656 B.
// ---------------------------------------------------------------------------
__global__ void __launch_bounds__(256, 1) attn_kernel(
    const bf16u* __restrict__ outy, const bf16u* __restrict__ keys,
    bf16u* __restrict__ ctxv)
{
    extern __shared__ char smem[];
    uint32* Qs  = (uint32*)smem;                    // [32][204] u32 (bf16 stride 408)
    uint32* Ks  = (uint32*)(smem + 26112);          // [32][204] u32
    bf16u*  Vt  = (bf16u*)(smem + 52224);           // [384][56] bf16 (V transposed)
    float*  Ss  = (float*)(smem + 95232);           // [4][32][33] f32 slabs
    bf16u*  Ph  = (bf16u*)(smem + 112128);          // [32][48] bf16
    bf16u*  Pl  = (bf16u*)(smem + 115200);          // [32][48] bf16
    float*  m_s = (float*)(smem + 118272);          // 32
    float*  l_s = m_s + 32;
    float*  al_s = m_s + 64;                        // end: 118656

    const int b = blockIdx.y;
    const int q0 = blockIdx.x * 32;
    const int tid = threadIdx.x;
    const int wave = tid >> 6, lane = tid & 63;
    const int lrow = lane & 31, lhalf = lane >> 5;

    for (int i = tid; i < 32 * 192; i += 256) {
        int q = i / 192, dp = i - q * 192;
        Qs[q * 204 + dp] = ((const uint32*)outy)[((size_t)(q0 + q) * 32 + b) * 192 + dp];
    }
    if (tid < 32) { m_s[tid] = -3e38f; l_s[tid] = 0.f; }

    f16v O[3];
    #pragma unroll
    for (int g = 0; g < 3; ++g)
        #pragma unroll
        for (int r = 0; r < 16; ++r) O[g][r] = 0.f;

    const int nkt = blockIdx.x + 1;
    for (int kt = 0; kt < nkt; ++kt) {
        const int k0 = kt * 32;
        __syncthreads();   // prev tile's QK (Ks) + PV (Vt) done before restage
        for (int i = tid; i < 32 * 192; i += 256) {
            int kk = i / 192, dp = i - kk * 192;
            size_t rb = ((size_t)(k0 + kk) * 32 + b) * 192;
            Ks[kk * 204 + dp] = ((const uint32*)keys)[rb + dp];
            uint32 vv = ((const uint32*)outy)[rb + dp];
            Vt[(2 * dp) * 56 + kk]     = (bf16u)(vv & 0xffffu);
            Vt[(2 * dp + 1) * 56 + kk] = (bf16u)(vv >> 16);
        }
        __syncthreads();

        // ---- QK^T partials: wave w owns d-chunks [w*6, w*6+6) of 24 ----
        {
            f16v s;
            #pragma unroll
            for (int r = 0; r < 16; ++r) s[r] = 0.f;
            #pragma unroll
            for (int i6 = 0; i6 < 6; ++i6) {
                const int kc = wave * 6 + i6;
                s8v a  = *(const s8v*)((const bf16u*)Qs + lrow * 408 + kc * 16 + lhalf * 8);
                s8v kb = *(const s8v*)((const bf16u*)Ks + lrow * 408 + kc * 16 + lhalf * 8);
                s = __builtin_amdgcn_mfma_f32_32x32x16_bf16(a, kb, s, 0, 0, 0);
            }
            float* ps = Ss + wave * 1056;
            #pragma unroll
            for (int r = 0; r < 16; ++r) {
                const int q = (r & 3) + 8 * (r >> 2) + 4 * lhalf;
                ps[q * 33 + lrow] = s[r];
            }
        }
        __syncthreads();

        // ---- softmax: thread q sums 4 slabs, online max/sum, P -> hi/lo ----
        if (tid < 32) {
            const int q = tid;
            float sv[32];
            float mt = m_s[q];
            #pragma unroll
            for (int k = 0; k < 32; ++k) {
                float s = Ss[q * 33 + k] + Ss[1056 + q * 33 + k]
                        + Ss[2112 + q * 33 + k] + Ss[3168 + q * 33 + k];
                s *= 0.051031036307982884f;   // 1/sqrt(384)
                sv[k] = ((k0 + k) <= (q0 + q)) ? s : -1e30f;
                mt = fmaxf(mt, sv[k]);
            }
            float alpha = __expf(m_s[q] - mt);
            float l = l_s[q] * alpha;
            #pragma unroll
            for (int k = 0; k < 32; ++k) {
                float pv = __expf(sv[k] - mt);
                l += pv;
                bf16u ph = f2bf(pv);
                Ph[q * 48 + k] = ph;
                Pl[q * 48 + k] = f2bf(pv - bf2f(ph));
            }
            m_s[q] = mt; l_s[q] = l; al_s[q] = alpha;
        }
        __syncthreads();

        // ---- rescale O by alpha, then PV: wave w owns d-groups w*3..w*3+2 ----
        {
            float ar[16];
            #pragma unroll
            for (int r = 0; r < 16; ++r)
                ar[r] = al_s[(r & 3) + 8 * (r >> 2) + 4 * lhalf];
            #pragma unroll
            for (int g = 0; g < 3; ++g)
                #pragma unroll
                for (int r = 0; r < 16; ++r) O[g][r] *= ar[r];

            s8v pa0 = *(const s8v*)(Ph + lrow * 48 + lhalf * 8);
            s8v pa1 = *(const s8v*)(Ph + lrow * 48 + 16 + lhalf * 8);
            s8v pl0 = *(const s8v*)(Pl + lrow * 48 + lhalf * 8);
            s8v pl1 = *(const s8v*)(Pl + lrow * 48 + 16 + lhalf * 8);
            #pragma unroll
            for (int g = 0; g < 3; ++g) {
                const int d = (wave * 3 + g) * 32 + lrow;
                s8v v0 = *(const s8v*)(Vt + d * 56 + lhalf * 8);
                s8v v1 = *(const s8v*)(Vt + d * 56 + 16 + lhalf * 8);
                O[g] = __builtin_amdgcn_mfma_f32_32x32x16_bf16(pa0, v0, O[g], 0, 0, 0);
                O[g] = __builtin_amdgcn_mfma_f32_32x32x16_bf16(pl0, v0, O[g], 0, 0, 0);
                O[g] = __builtin_amdgcn_mfma_f32_32x32x16_bf16(pa1, v1, O[g], 0, 0, 0);
                O[g] = __builtin_amdgcn_mfma_f32_32x32x16_bf16(pl1, v1, O[g], 0, 0, 0);
            }
        }
    }

    // ---- finalize: O * (1/l), stage bf16 in Ks region, coalesced store ----
    __syncthreads();
    if (tid < 32) al_s[tid] = 1.f / l_s[tid];
    __syncthreads();
    {
        float ir[16];
        #pragma unroll
        for (int r = 0; r < 16; ++r)
            ir[r] = al_s[(r & 3) + 8 * (r >> 2) + 4 * lhalf];
        bf16u* Os = (bf16u*)Ks;   // reuse: [32][408] bf16
        #pragma unroll
        for (int g = 0; g < 3; ++g) {
            const int d = (wave * 3 + g) * 32 + lrow;
            #pragma unroll
            for (int r = 0; r < 16; ++r) {
                const int q = (r & 3) + 8 * (r >> 2) + 4 * lhalf;
                Os[q * 408 + d] = f2bf(O[g][r] * ir[r]);
            }
        }
    }
    __syncthreads();
    for (int i = tid; i < 32 * 192; i += 256) {
        int q = i / 192, dp = i - q * 192;
        ((uint32*)ctxv)[((size_t)(q0 + q) * 32 + b) * 192 + dp] = Ks[q * 204 + dp];
    }
}

// ---------------------------------------------------------------------------
extern "C" void kernel_launch(void* const* d_in, const int* in_sizes, int n_in,
                              void* d_out, int out_size, void* d_ws, size_t ws_size,
                              hipStream_t stream) {
    (void)in_sizes; (void)n_in; (void)out_size; (void)ws_size;
    const int*   x        = (const int*)d_in[0];
    const float* context  = (const float*)d_in[1];
    const float* h_in     = (const float*)d_in[2];
    const float* c_in     = (const float*)d_in[3];
    const float* emb      = (const float*)d_in[4];
    const float* ctx_W    = (const float*)d_in[5];
    const float* ctx_b    = (const float*)d_in[6];
    const float* Wih0     = (const float*)d_in[7];
    const float* Wih_rest = (const float*)d_in[8];
    const float* Whh      = (const float*)d_in[9];
    const float* bih      = (const float*)d_in[10];
    const float* bhh      = (const float*)d_in[11];
    const float* Wa       = (const float*)d_in[12];
    const float* comb_W   = (const float*)d_in[13];
    const float* comb_b   = (const float*)d_in[14];
    const float* fc_W     = (const float*)d_in[15];
    const float* fc_b     = (const float*)d_in[16];
    float* out = (float*)d_out;

    // ---- workspace layout, ~76 MB peak ----
    char* wsb = (char*)d_ws;
    uint32* flags = (uint32*)(wsb + 0);               //  32 KB (192 lines)
    uint32* hbuf  = (uint32*)(wsb + 32768);           // 393 KB dense block-major
    uint32* y3bm  = (uint32*)(wsb + 458752);          // 25.17 MB [1024][6144]u32
    bf16u*  y3    = (bf16u*)(wsb + 25624576ull);      // 25.17 MB standard layout
    bf16u*  inp   = (bf16u*)(wsb + 50790400ull);      // 16.78 MB (region 25.17)
    bf16u*  keysu = (bf16u*)(wsb + 50790400ull);      // reuse (inp dead post-lstm)
    bf16u*  ctxvu = (bf16u*)(wsb + 458752);           // reuse (y3bm dead post-transpose)
    bf16u*  combu = (bf16u*)(wsb + 50790400ull);      // reuse (keys dead post-attn)

    hipMemsetAsync(d_ws, 0, 32768, stream);           // zero flags

    static int smem_set = 0;
    if (!smem_set) {
        hipFuncSetAttribute((const void*)lstm_wave_kernel,
                            hipFuncAttributeMaxDynamicSharedMemorySize, 67072);
        hipFuncSetAttribute((const void*)attn_kernel,
                            hipFuncAttributeMaxDynamicSharedMemorySize, 118656);
        smem_set = 1;
    }

    embed_ctx_kernel<<<2048, 128, 0, stream>>>(x, context, emb, ctx_W, ctx_b, inp);

    const size_t HS_OFF = (size_t)32768 * 100;
    // dynamic LDS: Wih planes (max 50176 B at l>0) + 4 gate slabs 16896 B
    lstm_wave_kernel<<<192, 256, 67072, stream>>>(
        inp, Wih0, Wih_rest, Whh, bih, bhh, h_in, c_in,
        y3bm, hbuf, flags, out + HS_OFF, out + HS_OFF + 49152);

    transpose_y_kernel<<<1024, 256, 0, stream>>>(y3bm, (uint32*)y3);

    // keys = y3 @ Wa^T
    gemm_kernel<<<dim3(6, 256), 256, 0, stream>>>(
        y3, nullptr, 384, Wa, nullptr, keysu, 32768, 384, 384, 1);
    // ctx_vec (flash attention, MFMA)
    attn_kernel<<<dim3(32, 32), 256, 118656, stream>>>(y3, keysu, ctxvu);
    // combined = tanh([y3, ctx] @ comb_W^T + b)
    gemm_kernel<<<dim3(6, 256), 256, 0, stream>>>(
        y3, ctxvu, 384, comb_W, comb_b, combu, 32768, 384, 768, 2);
    // logits = combined @ fc_W^T + fc_b  -> d_out permuted [b][t][100]
    gemm_kernel<<<dim3(2, 256), 256, 0, stream>>>(
        combu, nullptr, 384, fc_W, fc_b, out, 32768, 100, 384, 3);
}

// Round 11
// 5757.687 us; speedup vs baseline: 1.2916x; 1.0984x over previous
//
#include <hip/hip_runtime.h>

typedef unsigned int  uint32;
typedef unsigned long long u64;
typedef unsigned short bf16u;
typedef __attribute__((ext_vector_type(8))) short s8v;     // 8 bf16 (4 VGPRs)
typedef __attribute__((ext_vector_type(4))) float f4v;     // 16x16 MFMA acc
typedef __attribute__((ext_vector_type(16))) float f16v;   // 32x32 MFMA acc

#define PL   6144            // u32 per plane  (48 sub * 32 b * 4 u32)
#define PL64 3072            // u64 per plane
#define PAR  12288           // u32 per parity (2 planes)
#define HB2  24576           // u32 per layer  (2 parities)

__device__ __forceinline__ float fast_tanh(float x) {
    x = fminf(9.f, fmaxf(-9.f, x));
    float e = __expf(2.f * x);
    return (e - 1.f) / (e + 1.f);
}
__device__ __forceinline__ float sigmoidf(float x) {
    return 1.f / (1.f + __expf(-x));
}
__device__ __forceinline__ bf16u f2bf(float f) {
    uint32 u = __float_as_uint(f);
    u += 0x7fffu + ((u >> 16) & 1u);
    return (bf16u)(u >> 16);
}
__device__ __forceinline__ float bf2f(bf16u u) {
    return __uint_as_float(((uint32)u) << 16);
}
__device__ __forceinline__ uint32 pack2bf(float lo, float hi) {
    return (uint32)f2bf(lo) | ((uint32)f2bf(hi) << 16);
}
__device__ __forceinline__ float bflo(uint32 p) { return __uint_as_float(p << 16); }
__device__ __forceinline__ float bfhi(uint32 p) { return __uint_as_float(p & 0xffff0000u); }

// 16-B A-fragment load straight from the dense broadcast buffer to VGPRs.
// Agent-scope relaxed atomics -> bypass stale L1/L2, hit LLC.
__device__ __forceinline__ s8v ldfrag(const u64* p) {
    union { u64 q[2]; s8v v; } u;
    u.q[0] = __hip_atomic_load(p,     __ATOMIC_RELAXED, __HIP_MEMORY_SCOPE_AGENT);
    u.q[1] = __hip_atomic_load(p + 1, __ATOMIC_RELAXED, __HIP_MEMORY_SCOPE_AGENT);
    return u.v;
}

// ---------------------------------------------------------------------------
// Embedding + context projection -> inp [rt=t*32+b][256] bf16 (emb || ctx)
// ---------------------------------------------------------------------------
__global__ void __launch_bounds__(128) embed_ctx_kernel(
    const int* __restrict__ x, const float* __restrict__ ctx,
    const float* __restrict__ emb, const float* __restrict__ ctxW,
    const float* __restrict__ ctxb, bf16u* __restrict__ inp)
{
    const int r0 = blockIdx.x * 16;
    const int tid = threadIdx.x;
    __shared__ float cs[16][301];
    __shared__ int xs[16];
    for (int i = tid; i < 16 * 300; i += 128) {
        int row = i / 300, k = i - row * 300;
        int rt = r0 + row, b = rt & 31, t = rt >> 5;
        cs[row][k] = ctx[((size_t)b * 1024 + t) * 300 + k];
    }
    if (tid < 16) {
        int rt = r0 + tid;
        xs[tid] = x[(rt & 31) * 1024 + (rt >> 5)];
    }
    __syncthreads();
    float acc[16];
    #pragma unroll
    for (int row = 0; row < 16; ++row) acc[row] = 0.f;
    for (int k = 0; k < 300; ++k) {
        float w = ctxW[tid * 300 + k];
        #pragma unroll
        for (int row = 0; row < 16; ++row) acc[row] = fmaf(w, cs[row][k], acc[row]);
    }
    float bb = ctxb[tid];
    for (int row = 0; row < 16; ++row) {
        size_t base = (size_t)(r0 + row) * 256;
        inp[base + tid]       = f2bf(emb[xs[row] * 128 + tid]);
        inp[base + 128 + tid] = f2bf(acc[row] + bb);
    }
}

// ---------------------------------------------------------------------------
// MFMA GEMM (BM=128): C[M,N] = A[M,K](bf16) @ W[N,K]^T(f32 hi/lo).
// 256 threads = 4 waves; wave w owns rows [w*32, w*32+32) of the 128-row
// tile. A split at K0 between A0/A1. mode 1: bf16 out; 2: bf16+tanh;
// 3: f32 out, row rt->(b*1024+t) (logits). BN=64, BK=32.
// ---------------------------------------------------------------------------
__global__ void __launch_bounds__(256) gemm_kernel(
    const bf16u* __restrict__ A0, const bf16u* __restrict__ A1, int K0,
    const float* __restrict__ W, const float* __restrict__ bias1,
    void* __restrict__ Cout, int M, int N, int K, int mode)
{
    __shared__ bf16u As[128][40];
    __shared__ bf16u Whi[64][40];
    __shared__ bf16u Wlo[64][40];
    const int tid = threadIdx.x;
    const int bn = blockIdx.x * 64, bm = blockIdx.y * 128;
    const int wave = tid >> 6, lane = tid & 63;
    const int ncol = lane & 15, quad = lane >> 4;
    const int lr = tid >> 2, lk = (tid & 3) * 8;

    f4v acc[2][4];
    #pragma unroll
    for (int i = 0; i < 2; ++i)
        #pragma unroll
        for (int j = 0; j < 4; ++j) acc[i][j] = (f4v){0.f, 0.f, 0.f, 0.f};

    const int wrow = bn + lr;
    for (int k0 = 0; k0 < K; k0 += 32) {
        const bf16u* Ab; int kb, lda;
        if (k0 < K0) { Ab = A0; kb = k0; lda = K0; }
        else         { Ab = A1; kb = k0 - K0; lda = K - K0; }
        uint4 av0 = *(const uint4*)(Ab + (size_t)(bm + lr) * lda + kb + lk);
        uint4 av1 = *(const uint4*)(Ab + (size_t)(bm + 64 + lr) * lda + kb + lk);
        float4 w0 = make_float4(0.f, 0.f, 0.f, 0.f), w1 = w0;
        if (wrow < N) {
            const float* wp = W + (size_t)wrow * K + k0 + lk;
            w0 = *(const float4*)wp;
            w1 = *(const float4*)(wp + 4);
        }
        __syncthreads();
        *(uint4*)&As[lr][lk] = av0;
        *(uint4*)&As[64 + lr][lk] = av1;
        {
            bf16u h[8], l[8];
            float wf[8] = {w0.x, w0.y, w0.z, w0.w, w1.x, w1.y, w1.z, w1.w};
            #pragma unroll
            for (int j = 0; j < 8; ++j) {
                h[j] = f2bf(wf[j]);
                l[j] = f2bf(wf[j] - bf2f(h[j]));
            }
            #pragma unroll
            for (int j = 0; j < 8; ++j) Whi[lr][lk + j] = h[j];
            #pragma unroll
            for (int j = 0; j < 8; ++j) Wlo[lr][lk + j] = l[j];
        }
        __syncthreads();
        s8v aF[2], bH[4], bL[4];
        #pragma unroll
        for (int mt = 0; mt < 2; ++mt)
            aF[mt] = *(const s8v*)&As[wave * 32 + mt * 16 + ncol][quad * 8];
        #pragma unroll
        for (int nt = 0; nt < 4; ++nt) {
            bH[nt] = *(const s8v*)&Whi[nt * 16 + ncol][quad * 8];
            bL[nt] = *(const s8v*)&Wlo[nt * 16 + ncol][quad * 8];
        }
        #pragma unroll
        for (int mt = 0; mt < 2; ++mt)
            #pragma unroll
            for (int nt = 0; nt < 4; ++nt) {
                acc[mt][nt] = __builtin_amdgcn_mfma_f32_16x16x32_bf16(
                    aF[mt], bH[nt], acc[mt][nt], 0, 0, 0);
                acc[mt][nt] = __builtin_amdgcn_mfma_f32_16x16x32_bf16(
                    aF[mt], bL[nt], acc[mt][nt], 0, 0, 0);
            }
    }

    #pragma unroll
    for (int nt = 0; nt < 4; ++nt) {
        const int col = bn + nt * 16 + ncol;
        if (col >= N) continue;
        float bb = bias1 ? bias1[col] : 0.f;
        #pragma unroll
        for (int mt = 0; mt < 2; ++mt) {
            const int rowb = bm + wave * 32 + mt * 16 + quad * 4;
            if (mode == 3) {
                #pragma unroll
                for (int r = 0; r < 4; ++r) {
                    int row = rowb + r;
                    int b = row & 31, t = row >> 5;
                    ((float*)Cout)[((size_t)b * 1024 + t) * (size_t)N + col] =
                        acc[mt][nt][r] + bb;
                }
            } else {
                #pragma unroll
                for (int r = 0; r < 4; ++r) {
                    float v = acc[mt][nt][r] + bb;
                    if (mode == 2) v = fast_tanh(v);
                    ((bf16u*)Cout)[(size_t)(rowb + r) * N + col] = f2bf(v);
                }
            }
        }
    }
}

// ---------------------------------------------------------------------------
// Scoped flag barrier (round-6 verified): per-block flag on its OWN 128-B
// line (packing sync lines funnels traffic through few LLC slices: +2us/rd).
// Poll only the 3-layer stencil {l-1, l, l+1}.
// ---------------------------------------------------------------------------
__device__ __forceinline__ void scoped_barrier(uint32* flags, uint32 r,
                                               int tid, int l, int bid) {
    __syncthreads();
    if (tid == 0)
        __hip_atomic_store(&flags[bid * 32], r, __ATOMIC_RELAXED, __HIP_MEMORY_SCOPE_AGENT);
    const int lo = (l > 0) ? (l - 1) * 48 : 0;
    const int nf = ((l > 0) + 1 + (l < 3)) * 48;
    if (tid < nf) {
        while (__hip_atomic_load(&flags[(lo + tid) * 32], __ATOMIC_RELAXED,
                                 __HIP_MEMORY_SCOPE_AGENT) < r)
            __builtin_amdgcn_s_sleep(1);
    }
    __syncthreads();
}

// ---------------------------------------------------------------------------
// Layer-wavefront LSTM: 4 layers x 1024 steps, ONE launch, 1027 rounds.
// 192 blocks = 4 layers x 48 sub-blocks x 8 hidden dims. Gate MFMAs are
// 32x32x16, K-split across the 4 waves (each A-fragment loaded exactly once
// per block). Round-11: ALL A-frag ldfrags issued into explicit arrays
// BEFORE any MFMA — one LLC latency episode instead of per-chunk
// load->MFMA serialization (VGPR 128 showed the compiler wasn't hoisting;
// launch_bounds(256,1) = 1 wave/SIMD allows up to 512 VGPR).
// Partial tiles -> 4 LDS slabs summed by update threads. h broadcast:
// BLOCK-MAJOR DENSE [layer][parity][plane][sub][b][4u32]; A-frag
// (kt16,khalf,row) = 16 B at u64 index ((kt16*2+khalf)*32+row)*2.
// ---------------------------------------------------------------------------
__global__ void __launch_bounds__(256, 1) lstm_wave_kernel(
    const bf16u* __restrict__ inp,   // [t*32+b][256] bf16
    const float* __restrict__ Wih0,  // [1536][256]
    const float* __restrict__ WihR,  // [3][1536][384]
    const float* __restrict__ Whh,   // [4][1536][384]
    const float* __restrict__ bih, const float* __restrict__ bhh,
    const float* __restrict__ h_in, const float* __restrict__ c_in,
    uint32* __restrict__ y3bm,       // [1024][48][32][4] u32 (hi plane only)
    uint32* __restrict__ hbuf,       // [4][2][2][48][32][4] u32
    uint32* __restrict__ flags,      // 192 flags, 128-B spaced
    float* __restrict__ hs_out, float* __restrict__ cs_out)
{
    extern __shared__ char sm[];
    const int tid = threadIdx.x, bid = blockIdx.x;
    const int l = bid / 48, sub = bid - l * 48;
    const int j0 = sub * 8;
    const int wave = tid >> 6, lane = tid & 63;
    const int row32 = lane & 31;              // A row (batch) / B row (gate)
    const int khalf = lane >> 5;              // k-half within a 16-chunk
    const int n = row32;                      // local gate-row for B/D col

    const int Kx = l ? 384 : 256;
    const int WSTR = l ? 392 : 264;           // padded bf16 stride
    const int wbytes = 2 * 32 * WSTR * 2;     // Wih planes bytes
    bf16u* wlds  = (bf16u*)sm;
    float* gates = (float*)(sm + wbytes);     // 4 slabs x 1056 f32 = 16896 B

    const float* WhhL = Whh + (size_t)l * 1536 * 384;
    const float* WihL = l ? (WihR + (size_t)(l - 1) * 1536 * 384) : Wih0;
    const float* bihL = bih + l * 1536;
    const float* bhhL = bhh + l * 1536;
    uint32* hbL = hbuf + (size_t)l * HB2;
    uint32* ybL = l ? (hbuf + (size_t)(l - 1) * HB2) : nullptr;

    const int h0c = wave * 6;                 // this wave's h/y k16-chunks
    const int x0c = wave * 4;                 // l0 x k16-chunks

    // ---- Whh B-frags in registers (hi/lo): rows = ALL 32 local gates,
    //      k = this wave's 6 chunks x khalf ----
    s8v Bh6[6], Bl6[6];
    {
        const int wrow = (n >> 3) * 384 + j0 + (n & 7);
        #pragma unroll
        for (int i = 0; i < 6; ++i) {
            const float* wp = WhhL + (size_t)wrow * 384 + (h0c + i) * 16 + khalf * 8;
            s8v hi, lo;
            #pragma unroll
            for (int j = 0; j < 8; ++j) {
                float w = wp[j];
                bf16u wh = f2bf(w);
                bf16u wl = f2bf(w - bf2f(wh));
                hi[j] = (short)wh; lo[j] = (short)wl;
            }
            Bh6[i] = hi; Bl6[i] = lo;
        }
    }
    // ---- Wih slice into LDS (hi/lo planes) ----
    for (int r2 = 0; r2 < 32; ++r2) {
        int rg = (r2 >> 3) * 384 + j0 + (r2 & 7);
        for (int k = tid; k < Kx; k += 256) {
            float w = WihL[(size_t)rg * Kx + k];
            bf16u wh = f2bf(w);
            wlds[r2 * WSTR + k] = wh;
            wlds[32 * WSTR + r2 * WSTR + k] = f2bf(w - bf2f(wh));
        }
    }

    // update role: tid<128 owns (batch ub, dim pair jg0, jg0+1)
    const int ub = tid & 31, jp = tid >> 5;          // jp 0..3 for tid<128
    const int jg0 = j0 + 2 * jp;
    const int wbase = (sub * 32 + ub) * 4 + jp;      // dense u32 index
    float c0r = 0.f, c1r = 0.f, h0l = 0.f, h1l = 0.f;
    float bI0 = 0, bF0 = 0, bG0 = 0, bO0 = 0, bI1 = 0, bF1 = 0, bG1 = 0, bO1 = 0;

    if (tid < 128) {
        bI0 = bihL[jg0] + bhhL[jg0];
        bF0 = bihL[384 + jg0] + bhhL[384 + jg0];
        bG0 = bihL[768 + jg0] + bhhL[768 + jg0];
        bO0 = bihL[1152 + jg0] + bhhL[1152 + jg0];
        bI1 = bihL[jg0 + 1] + bhhL[jg0 + 1];
        bF1 = bihL[384 + jg0 + 1] + bhhL[384 + jg0 + 1];
        bG1 = bihL[768 + jg0 + 1] + bhhL[768 + jg0 + 1];
        bO1 = bihL[1152 + jg0 + 1] + bhhL[1152 + jg0 + 1];
        float ha = h_in[(size_t)l * 12288 + ub * 384 + jg0];
        float hb = h_in[(size_t)l * 12288 + ub * 384 + jg0 + 1];
        bf16u ha_h = f2bf(ha); bf16u ha_l = f2bf(ha - bf2f(ha_h));
        bf16u hb_h = f2bf(hb); bf16u hb_l = f2bf(hb - bf2f(hb_h));
        __hip_atomic_store(&hbL[wbase],
                           (uint32)ha_h | ((uint32)hb_h << 16),
                           __ATOMIC_RELAXED, __HIP_MEMORY_SCOPE_AGENT);
        __hip_atomic_store(&hbL[PL + wbase],
                           (uint32)ha_l | ((uint32)hb_l << 16),
                           __ATOMIC_RELAXED, __HIP_MEMORY_SCOPE_AGENT);
        c0r = c_in[(size_t)l * 12288 + ub * 384 + jg0];
        c1r = c_in[(size_t)l * 12288 + ub * 384 + jg0 + 1];
    }
    scoped_barrier(flags, 1u, tid, l, bid);

    for (int r = 0; r < 1027; ++r) {
        const int t = r - l;
        if ((unsigned)t < 1024u) {
            const u64* hB = (const u64*)(hbL + (t & 1) * PAR);
            uint32* hW = hbL + ((t + 1) & 1) * PAR;

            f16v cHH = {0.f,0.f,0.f,0.f,0.f,0.f,0.f,0.f,
                        0.f,0.f,0.f,0.f,0.f,0.f,0.f,0.f};
            f16v cLH = cHH, cHL = cHH;

            // ---- phase 1: issue ALL A-frag loads into arrays (no MFMA
            // dependency until every load is in flight) ----
            s8v Ah[6], Al[6];
            #pragma unroll
            for (int i = 0; i < 6; ++i) {
                const int co = (((h0c + i) * 2 + khalf) * 32 + row32) * 2;
                Ah[i] = ldfrag(hB + co);
                Al[i] = ldfrag(hB + PL64 + co);
            }

            if (l) {
                const u64* yB = (const u64*)(ybL + ((t + 1) & 1) * PAR);
                s8v Ayh[6], Ayl[6];
                #pragma unroll
                for (int i = 0; i < 6; ++i) {
                    const int co = (((h0c + i) * 2 + khalf) * 32 + row32) * 2;
                    Ayh[i] = ldfrag(yB + co);
                    Ayl[i] = ldfrag(yB + PL64 + co);
                }
                // ---- phase 2: MFMAs (h first — its loads issued first) ----
                #pragma unroll
                for (int i = 0; i < 6; ++i) {
                    cHH = __builtin_amdgcn_mfma_f32_32x32x16_bf16(Ah[i], Bh6[i], cHH, 0, 0, 0);
                    cLH = __builtin_amdgcn_mfma_f32_32x32x16_bf16(Al[i], Bh6[i], cLH, 0, 0, 0);
                    cHL = __builtin_amdgcn_mfma_f32_32x32x16_bf16(Ah[i], Bl6[i], cHL, 0, 0, 0);
                }
                #pragma unroll
                for (int i = 0; i < 6; ++i) {
                    const int kt = h0c + i;
                    s8v Bxh = *(const s8v*)&wlds[n * 392 + kt * 16 + khalf * 8];
                    s8v Bxl = *(const s8v*)&wlds[32 * 392 + n * 392 + kt * 16 + khalf * 8];
                    cHH = __builtin_amdgcn_mfma_f32_32x32x16_bf16(Ayh[i], Bxh, cHH, 0, 0, 0);
                    cLH = __builtin_amdgcn_mfma_f32_32x32x16_bf16(Ayl[i], Bxh, cLH, 0, 0, 0);
                    cHL = __builtin_amdgcn_mfma_f32_32x32x16_bf16(Ayh[i], Bxl, cHL, 0, 0, 0);
                }
            } else {
                const uint4* irow = (const uint4*)(inp + ((size_t)t * 32 + row32) * 256);
                s8v Ai[4];
                #pragma unroll
                for (int i = 0; i < 4; ++i) {
                    union { uint4 u; s8v v; } cv;
                    cv.u = irow[(x0c + i) * 2 + khalf];
                    Ai[i] = cv.v;
                }
                #pragma unroll
                for (int i = 0; i < 6; ++i) {
                    cHH = __builtin_amdgcn_mfma_f32_32x32x16_bf16(Ah[i], Bh6[i], cHH, 0, 0, 0);
                    cLH = __builtin_amdgcn_mfma_f32_32x32x16_bf16(Al[i], Bh6[i], cLH, 0, 0, 0);
                    cHL = __builtin_amdgcn_mfma_f32_32x32x16_bf16(Ah[i], Bl6[i], cHL, 0, 0, 0);
                }
                #pragma unroll
                for (int i = 0; i < 4; ++i) {
                    const int kt = x0c + i;
                    s8v Bxh = *(const s8v*)&wlds[n * 264 + kt * 16 + khalf * 8];
                    s8v Bxl = *(const s8v*)&wlds[32 * 264 + n * 264 + kt * 16 + khalf * 8];
                    cHH = __builtin_amdgcn_mfma_f32_32x32x16_bf16(Ai[i], Bxh, cHH, 0, 0, 0);
                    cHL = __builtin_amdgcn_mfma_f32_32x32x16_bf16(Ai[i], Bxl, cHL, 0, 0, 0);
                }
            }
            // ---- partial tile -> this wave's LDS slab ----
            {
                float* ps = gates + wave * 1056;
                #pragma unroll
                for (int reg = 0; reg < 16; ++reg) {
                    const int brow = (reg & 3) + 8 * (reg >> 2) + 4 * khalf;
                    ps[n * 33 + brow] = cHH[reg] + cLH[reg] + cHL[reg];
                }
            }
            __syncthreads();

            // ---- cell update: tid<128, 2 dims each; sum 4 K-partials ----
            if (tid < 128) {
                const int jj0 = 2 * jp, jj1 = 2 * jp + 1;
                #define GS(g) (gates[(g) * 33 + ub] + gates[1056 + (g) * 33 + ub] + \
                               gates[2112 + (g) * 33 + ub] + gates[3168 + (g) * 33 + ub])
                float pi0 = GS(jj0)      + bI0;
                float pf0 = GS(8 + jj0)  + bF0;
                float pg0 = GS(16 + jj0) + bG0;
                float po0 = GS(24 + jj0) + bO0;
                float pi1 = GS(jj1)      + bI1;
                float pf1 = GS(8 + jj1)  + bF1;
                float pg1 = GS(16 + jj1) + bG1;
                float po1 = GS(24 + jj1) + bO1;
                #undef GS
                c0r = sigmoidf(pf0) * c0r + sigmoidf(pi0) * fast_tanh(pg0);
                c1r = sigmoidf(pf1) * c1r + sigmoidf(pi1) * fast_tanh(pg1);
                float hv0 = sigmoidf(po0) * fast_tanh(c0r);
                float hv1 = sigmoidf(po1) * fast_tanh(c1r);
                h0l = hv0; h1l = hv1;
                bf16u h0h = f2bf(hv0); bf16u h0lo = f2bf(hv0 - bf2f(h0h));
                bf16u h1h = f2bf(hv1); bf16u h1lo = f2bf(hv1 - bf2f(h1h));
                uint32 hiw = (uint32)h0h | ((uint32)h1h << 16);
                uint32 low = (uint32)h0lo | ((uint32)h1lo << 16);
                __hip_atomic_store(&hW[wbase], hiw,
                                   __ATOMIC_RELAXED, __HIP_MEMORY_SCOPE_AGENT);
                __hip_atomic_store(&hW[PL + wbase], low,
                                   __ATOMIC_RELAXED, __HIP_MEMORY_SCOPE_AGENT);
                if (l == 3)
                    y3bm[(size_t)t * 6144 + wbase] = hiw;   // dense full lines
            }
        }
        scoped_barrier(flags, (uint32)(r + 2), tid, l, bid);
    }

    if (tid < 128) {
        hs_out[(size_t)l * 12288 + ub * 384 + jg0]     = h0l;
        hs_out[(size_t)l * 12288 + ub * 384 + jg0 + 1] = h1l;
        cs_out[(size_t)l * 12288 + ub * 384 + jg0]     = c0r;
        cs_out[(size_t)l * 12288 + ub * 384 + jg0 + 1] = c1r;
    }
}

// ---------------------------------------------------------------------------
// y3 block-major [t][48][32][4u32] -> standard [t*32+b][384] bf16.
// One block per t; LDS transpose, coalesced both sides.
// ---------------------------------------------------------------------------
__global__ void __launch_bounds__(256) transpose_y_kernel(
    const uint32* __restrict__ in, uint32* __restrict__ out)
{
    const int t = blockIdx.x;
    const int tid = threadIdx.x;
    __shared__ uint32 lds[32 * 197];
    const uint32* src = in + (size_t)t * 6144;
    #pragma unroll
    for (int k = 0; k < 24; ++k) {
        int i = k * 256 + tid;
        int sub = i >> 7, b = (i >> 2) & 31, q = i & 3;
        lds[b * 197 + sub * 4 + q] = src[i];
    }
    __syncthreads();
    uint32* dst = out + (size_t)t * 32 * 192;
    #pragma unroll
    for (int k = 0; k < 24; ++k) {
        int i = k * 256 + tid;
        int b = i / 192, c = i - b * 192;
        dst[b * 192 + c] = lds[b * 197 + c];
    }
}

// ---------------------------------------------------------------------------
// Causal flash attention, MFMA version (round-9 verified). Per block: 32
// q-rows of one batch; k-tiles of 32 keys. QK^T: 32x32x16 MFMAs, d-dim
// split across 4 waves -> 4 partial slabs. Softmax (32 threads) sums slabs,
// online max/sum, P as hi/lo bf16. PV: A=P, B=V^T (transposed at staging),
// O in registers with alpha-rescale. Dynamic LDS 118656 B.
// ---------------------------------------------------------------------------
__global__ void __launch_bounds__(256, 1) attn_kernel(
    const bf16u* __restrict__ outy, const bf16u* __restrict__ keys,
    bf16u* __restrict__ ctxv)
{
    extern __shared__ char smem[];
    uint32* Qs  = (uint32*)smem;                    // [32][204] u32 (bf16 stride 408)
    uint32* Ks  = (uint32*)(smem + 26112);          // [32][204] u32
    bf16u*  Vt  = (bf16u*)(smem + 52224);           // [384][56] bf16 (V transposed)
    float*  Ss  = (float*)(smem + 95232);           // [4][32][33] f32 slabs
    bf16u*  Ph  = (bf16u*)(smem + 112128);          // [32][48] bf16
    bf16u*  Pl  = (bf16u*)(smem + 115200);          // [32][48] bf16
    float*  m_s = (float*)(smem + 118272);          // 32
    float*  l_s = m_s + 32;
    float*  al_s = m_s + 64;                        // end: 118656

    const int b = blockIdx.y;
    const int q0 = blockIdx.x * 32;
    const int tid = threadIdx.x;
    const int wave = tid >> 6, lane = tid & 63;
    const int lrow = lane & 31, lhalf = lane >> 5;

    for (int i = tid; i < 32 * 192; i += 256) {
        int q = i / 192, dp = i - q * 192;
        Qs[q * 204 + dp] = ((const uint32*)outy)[((size_t)(q0 + q) * 32 + b) * 192 + dp];
    }
    if (tid < 32) { m_s[tid] = -3e38f; l_s[tid] = 0.f; }

    f16v O[3];
    #pragma unroll
    for (int g = 0; g < 3; ++g)
        #pragma unroll
        for (int r = 0; r < 16; ++r) O[g][r] = 0.f;

    const int nkt = blockIdx.x + 1;
    for (int kt = 0; kt < nkt; ++kt) {
        const int k0 = kt * 32;
        __syncthreads();   // prev tile's QK (Ks) + PV (Vt) done before restage
        for (int i = tid; i < 32 * 192; i += 256) {
            int kk = i / 192, dp = i - kk * 192;
            size_t rb = ((size_t)(k0 + kk) * 32 + b) * 192;
            Ks[kk * 204 + dp] = ((const uint32*)keys)[rb + dp];
            uint32 vv = ((const uint32*)outy)[rb + dp];
            Vt[(2 * dp) * 56 + kk]     = (bf16u)(vv & 0xffffu);
            Vt[(2 * dp + 1) * 56 + kk] = (bf16u)(vv >> 16);
        }
        __syncthreads();

        // ---- QK^T partials: wave w owns d-chunks [w*6, w*6+6) of 24 ----
        {
            f16v s;
            #pragma unroll
            for (int r = 0; r < 16; ++r) s[r] = 0.f;
            #pragma unroll
            for (int i6 = 0; i6 < 6; ++i6) {
                const int kc = wave * 6 + i6;
                s8v a  = *(const s8v*)((const bf16u*)Qs + lrow * 408 + kc * 16 + lhalf * 8);
                s8v kb = *(const s8v*)((const bf16u*)Ks + lrow * 408 + kc * 16 + lhalf * 8);
                s = __builtin_amdgcn_mfma_f32_32x32x16_bf16(a, kb, s, 0, 0, 0);
            }
            float* ps = Ss + wave * 1056;
            #pragma unroll
            for (int r = 0; r < 16; ++r) {
                const int q = (r & 3) + 8 * (r >> 2) + 4 * lhalf;
                ps[q * 33 + lrow] = s[r];
            }
        }
        __syncthreads();

        // ---- softmax: thread q sums 4 slabs, online max/sum, P -> hi/lo ----
        if (tid < 32) {
            const int q = tid;
            float sv[32];
            float mt = m_s[q];
            #pragma unroll
            for (int k = 0; k < 32; ++k) {
                float s = Ss[q * 33 + k] + Ss[1056 + q * 33 + k]
                        + Ss[2112 + q * 33 + k] + Ss[3168 + q * 33 + k];
                s *= 0.051031036307982884f;   // 1/sqrt(384)
                sv[k] = ((k0 + k) <= (q0 + q)) ? s : -1e30f;
                mt = fmaxf(mt, sv[k]);
            }
            float alpha = __expf(m_s[q] - mt);
            float l = l_s[q] * alpha;
            #pragma unroll
            for (int k = 0; k < 32; ++k) {
                float pv = __expf(sv[k] - mt);
                l += pv;
                bf16u ph = f2bf(pv);
                Ph[q * 48 + k] = ph;
                Pl[q * 48 + k] = f2bf(pv - bf2f(ph));
            }
            m_s[q] = mt; l_s[q] = l; al_s[q] = alpha;
        }
        __syncthreads();

        // ---- rescale O by alpha, then PV: wave w owns d-groups w*3..w*3+2 ----
        {
            float ar[16];
            #pragma unroll
            for (int r = 0; r < 16; ++r)
                ar[r] = al_s[(r & 3) + 8 * (r >> 2) + 4 * lhalf];
            #pragma unroll
            for (int g = 0; g < 3; ++g)
                #pragma unroll
                for (int r = 0; r < 16; ++r) O[g][r] *= ar[r];

            s8v pa0 = *(const s8v*)(Ph + lrow * 48 + lhalf * 8);
            s8v pa1 = *(const s8v*)(Ph + lrow * 48 + 16 + lhalf * 8);
            s8v pl0 = *(const s8v*)(Pl + lrow * 48 + lhalf * 8);
            s8v pl1 = *(const s8v*)(Pl + lrow * 48 + 16 + lhalf * 8);
            #pragma unroll
            for (int g = 0; g < 3; ++g) {
                const int d = (wave * 3 + g) * 32 + lrow;
                s8v v0 = *(const s8v*)(Vt + d * 56 + lhalf * 8);
                s8v v1 = *(const s8v*)(Vt + d * 56 + 16 + lhalf * 8);
                O[g] = __builtin_amdgcn_mfma_f32_32x32x16_bf16(pa0, v0, O[g], 0, 0, 0);
                O[g] = __builtin_amdgcn_mfma_f32_32x32x16_bf16(pl0, v0, O[g], 0, 0, 0);
                O[g] = __builtin_amdgcn_mfma_f32_32x32x16_bf16(pa1, v1, O[g], 0, 0, 0);
                O[g] = __builtin_amdgcn_mfma_f32_32x32x16_bf16(pl1, v1, O[g], 0, 0, 0);
            }
        }
    }

    // ---- finalize: O * (1/l), stage bf16 in Ks region, coalesced store ----
    __syncthreads();
    if (tid < 32) al_s[tid] = 1.f / l_s[tid];
    __syncthreads();
    {
        float ir[16];
        #pragma unroll
        for (int r = 0; r < 16; ++r)
            ir[r] = al_s[(r & 3) + 8 * (r >> 2) + 4 * lhalf];
        bf16u* Os = (bf16u*)Ks;   // reuse: [32][408] bf16
        #pragma unroll
        for (int g = 0; g < 3; ++g) {
            const int d = (wave * 3 + g) * 32 + lrow;
            #pragma unroll
            for (int r = 0; r < 16; ++r) {
                const int q = (r & 3) + 8 * (r >> 2) + 4 * lhalf;
                Os[q * 408 + d] = f2bf(O[g][r] * ir[r]);
            }
        }
    }
    __syncthreads();
    for (int i = tid; i < 32 * 192; i += 256) {
        int q = i / 192, dp = i - q * 192;
        ((uint32*)ctxv)[((size_t)(q0 + q) * 32 + b) * 192 + dp] = Ks[q * 204 + dp];
    }
}

// ---------------------------------------------------------------------------
extern "C" void kernel_launch(void* const* d_in, const int* in_sizes, int n_in,
                              void* d_out, int out_size, void* d_ws, size_t ws_size,
                              hipStream_t stream) {
    (void)in_sizes; (void)n_in; (void)out_size; (void)ws_size;
    const int*   x        = (const int*)d_in[0];
    const float* context  = (const float*)d_in[1];
    const float* h_in     = (const float*)d_in[2];
    const float* c_in     = (const float*)d_in[3];
    const float* emb      = (const float*)d_in[4];
    const float* ctx_W    = (const float*)d_in[5];
    const float* ctx_b    = (const float*)d_in[6];
    const float* Wih0     = (const float*)d_in[7];
    const float* Wih_rest = (const float*)d_in[8];
    const float* Whh      = (const float*)d_in[9];
    const float* bih      = (const float*)d_in[10];
    const float* bhh      = (const float*)d_in[11];
    const float* Wa       = (const float*)d_in[12];
    const float* comb_W   = (const float*)d_in[13];
    const float* comb_b   = (const float*)d_in[14];
    const float* fc_W     = (const float*)d_in[15];
    const float* fc_b     = (const float*)d_in[16];
    float* out = (float*)d_out;

    // ---- workspace layout, ~76 MB peak ----
    char* wsb = (char*)d_ws;
    uint32* flags = (uint32*)(wsb + 0);               //  32 KB (192 lines)
    uint32* hbuf  = (uint32*)(wsb + 32768);           // 393 KB dense block-major
    uint32* y3bm  = (uint32*)(wsb + 458752);          // 25.17 MB [1024][6144]u32
    bf16u*  y3    = (bf16u*)(wsb + 25624576ull);      // 25.17 MB standard layout
    bf16u*  inp   = (bf16u*)(wsb + 50790400ull);      // 16.78 MB (region 25.17)
    bf16u*  keysu = (bf16u*)(wsb + 50790400ull);      // reuse (inp dead post-lstm)
    bf16u*  ctxvu = (bf16u*)(wsb + 458752);           // reuse (y3bm dead post-transpose)
    bf16u*  combu = (bf16u*)(wsb + 50790400ull);      // reuse (keys dead post-attn)

    hipMemsetAsync(d_ws, 0, 32768, stream);           // zero flags

    static int smem_set = 0;
    if (!smem_set) {
        hipFuncSetAttribute((const void*)lstm_wave_kernel,
                            hipFuncAttributeMaxDynamicSharedMemorySize, 67072);
        hipFuncSetAttribute((const void*)attn_kernel,
                            hipFuncAttributeMaxDynamicSharedMemorySize, 118656);
        smem_set = 1;
    }

    embed_ctx_kernel<<<2048, 128, 0, stream>>>(x, context, emb, ctx_W, ctx_b, inp);

    const size_t HS_OFF = (size_t)32768 * 100;
    // dynamic LDS: Wih planes (max 50176 B at l>0) + 4 gate slabs 16896 B
    lstm_wave_kernel<<<192, 256, 67072, stream>>>(
        inp, Wih0, Wih_rest, Whh, bih, bhh, h_in, c_in,
        y3bm, hbuf, flags, out + HS_OFF, out + HS_OFF + 49152);

    transpose_y_kernel<<<1024, 256, 0, stream>>>(y3bm, (uint32*)y3);

    // keys = y3 @ Wa^T
    gemm_kernel<<<dim3(6, 256), 256, 0, stream>>>(
        y3, nullptr, 384, Wa, nullptr, keysu, 32768, 384, 384, 1);
    // ctx_vec (flash attention, MFMA)
    attn_kernel<<<dim3(32, 32), 256, 118656, stream>>>(y3, keysu, ctxvu);
    // combined = tanh([y3, ctx] @ comb_W^T + b)
    gemm_kernel<<<dim3(6, 256), 256, 0, stream>>>(
        y3, ctxvu, 384, comb_W, comb_b, combu, 32768, 384, 768, 2);
    // logits = combined @ fc_W^T + fc_b  -> d_out permuted [b][t][100]
    gemm_kernel<<<dim3(2, 256), 256, 0, stream>>>(
        combu, nullptr, 384, fc_W, fc_b, out, 32768, 100, 384, 3);
}